// Round 5
// baseline (672.236 us; speedup 1.0000x reference)
//
#include <hip/hip_runtime.h>
#include <hip/hip_cooperative_groups.h>
#include <stdint.h>

namespace cg = cooperative_groups;

#define Hdim 512
#define Bdim 128
#define Ldim 512
#define Vdim 2048

typedef unsigned short u16;
using f32x4  = float  __attribute__((ext_vector_type(4)));
using bf16x8 = __bf16 __attribute__((ext_vector_type(8)));

__device__ inline u16 f2bf(float x) {
  uint32_t u = __float_as_uint(x);
  u += 0x7fffu + ((u >> 16) & 1u);   // RNE
  return (u16)(u >> 16);
}
__device__ inline uint32_t pk2(float lo, float hi) {
  return (uint32_t)f2bf(lo) | ((uint32_t)f2bf(hi) << 16);
}
__device__ inline float fast_tanh(float x) {
  return 1.0f - 2.0f / (__expf(2.0f * x) + 1.0f);
}
__device__ inline float fast_sig(float x) { return 1.0f / (1.0f + __expf(-x)); }

__device__ inline bf16x8 pack_bf8(float4 x, float4 y) {
  union { uint32_t d[4]; bf16x8 v; } r;
  r.d[0] = pk2(x.x, x.y); r.d[1] = pk2(x.z, x.w);
  r.d[2] = pk2(y.x, y.y); r.d[3] = pk2(y.z, y.w);
  return r.v;
}

struct KArgs {
  const int* ids; const float* lh; const float* wdv; const float* enc;
  const void* mask; const float* attn_W; const float* attn_b; const float* scW;
  const float* cat_W; const float* cat_b;
  const float* W_ih0; const float* W_hh0; const float* b_ih0; const float* b_hh0;
  const float* W_ih1; const float* W_hh1; const float* b_ih1; const float* b_hh1;
  float* out; float* h0o; float* h1o;
  float* qW; float* scores; float* biasg0; float* biasg1; int* flag;
  u16* arena; u16* X0bf; u16* X1bf; u16* c1bf;
};

// LDS budget: attn stage is max: As 128x40 u16 (10240B) + Bs 512x40 u16 (40960B)
// + part 8x128 f32 (4096B) = 55296B
#define SMEM_BYTES 55296

// GRU GEMM: M=128, 16 gate-cols per block (gate-interleaved 4o+g), fused combine.
__device__ inline void gru_stage(const KArgs& a, const u16* X, int ldx, const u16* Wp,
                                 const float* biasg, const float* hprev,
                                 float* hout, u16* xdst, int K,
                                 int blk, int t, float* ctile) {
  int lane = t & 63, wv = t >> 6, fr = lane & 15, g = lane >> 4, kof = g * 8;
  int n0 = blk * 16;
  f32x4 acc = {0.f, 0.f, 0.f, 0.f};
  const u16* Xr = X + (size_t)(wv * 16 + fr) * ldx;
  const u16* Wr = Wp + (size_t)(n0 + fr) * K;
#pragma unroll 4
  for (int kt = 0; kt < K; kt += 32) {
    bf16x8 av = *(const bf16x8*)(Xr + kt + kof);
    bf16x8 bv = *(const bf16x8*)(Wr + kt + kof);
    acc = __builtin_amdgcn_mfma_f32_16x16x32_bf16(av, bv, acc, 0, 0, 0);
  }
  float vb = biasg[n0 + fr];
#pragma unroll
  for (int j = 0; j < 4; ++j)
    ctile[(wv * 16 + g * 4 + j) * 20 + fr] = acc[j] + vb;
  __syncthreads();
  {
    int b2 = t >> 2, oj = t & 3;
    float cr  = ctile[b2 * 20 + oj * 4 + 0];
    float cz  = ctile[b2 * 20 + oj * 4 + 1];
    float ci  = ctile[b2 * 20 + oj * 4 + 2];
    float chh = ctile[b2 * 20 + oj * 4 + 3];
    int o = blk * 4 + oj;
    float r = fast_sig(cr), z = fast_sig(cz);
    float n = tanhf(ci + r * chh);
    float h = (1.0f - z) * n + z * hprev[b2 * 512 + o];
    hout[b2 * 512 + o] = h;
    xdst[b2 * 1024 + o] = f2bf(h);
  }
}

__global__ __launch_bounds__(512, 2) void mega_kernel(KArgs a) {
  extern __shared__ __align__(16) unsigned char smem[];
  cg::grid_group gridg = cg::this_grid();
  const int blk = blockIdx.x, t = threadIdx.x;
  const int lane = t & 63, wid = t >> 6;
  const int fr = lane & 15, g = lane >> 4, kof = g * 8;

  // ================= Phase A: prep + qW =================
  if (blk < 16) {
    // qW = q @ attn_W[:, :512]^T + attn_b   (f32 inputs, in-reg bf16 cvt)
    int mh = wid & 3, nh = wid >> 2;
    int n0 = blk * 32 + nh * 16;
    int rb0 = mh * 32;
    f32x4 ac0 = {0.f, 0.f, 0.f, 0.f}, ac1 = {0.f, 0.f, 0.f, 0.f};
    const float* q = a.lh + 65536;
#pragma unroll 2
    for (int kt = 0; kt < 512; kt += 32) {
      const float* qr0 = q + (size_t)(rb0 + fr) * 512 + kt + kof;
      const float* qr1 = qr0 + 16 * 512;
      const float* wr  = a.attn_W + (size_t)(n0 + fr) * 1024 + kt + kof;
      float4 x0 = *(const float4*)qr0, x1 = *(const float4*)(qr0 + 4);
      float4 y0 = *(const float4*)qr1, y1 = *(const float4*)(qr1 + 4);
      float4 w0 = *(const float4*)wr,  w1 = *(const float4*)(wr + 4);
      bf16x8 A0 = pack_bf8(x0, x1), A1 = pack_bf8(y0, y1), Bb = pack_bf8(w0, w1);
      ac0 = __builtin_amdgcn_mfma_f32_16x16x32_bf16(A0, Bb, ac0, 0, 0, 0);
      ac1 = __builtin_amdgcn_mfma_f32_16x16x32_bf16(A1, Bb, ac1, 0, 0, 0);
    }
    float vb = a.attn_b[n0 + fr];
#pragma unroll
    for (int j = 0; j < 4; ++j) {
      a.qW[(size_t)(rb0 + g * 4 + j) * 512 + n0 + fr]      = ac0[j] + vb;
      a.qW[(size_t)(rb0 + 16 + g * 4 + j) * 512 + n0 + fr] = ac1[j] + vb;
    }
  } else if (blk < 255) {
    const int NT = 239 * 512;
    const int ARENA_Q = 1507328;
    const int T_TOTAL = ARENA_Q + 1024 + 3 * 16384;
    int tid = (blk - 16) * 512 + t;
    for (int i = tid; i < T_TOTAL; i += NT) {
      if (i < ARENA_Q) {
        int e = i * 4;
        float4 v = {0.f, 0.f, 0.f, 0.f};
        if (e < 262144) {                      // Wenc = attn_W[:, 512:]
          int o = e >> 9, k = e & 511;
          v = *(const float4*)(a.attn_W + (size_t)o * 1024 + 512 + k);
        } else if (e < 786432) {               // Wcat
          int e2 = e - 262144; int o = e2 >> 10, k = e2 & 1023;
          v = *(const float4*)(a.cat_W + (size_t)o * 1024 + k);
        } else if (e < 3932160) {              // Wg0p [2048=4o+g][1536]
          int e2 = e - 786432; int row = e2 / 1536, k = e2 % 1536;
          int o = row >> 2, gt = row & 3;
          if (gt == 0)      v = (k < 1024) ? *(const float4*)(a.W_ih0 + (size_t)o * 1024 + k)
                                           : *(const float4*)(a.W_hh0 + (size_t)o * 512 + k - 1024);
          else if (gt == 1) v = (k < 1024) ? *(const float4*)(a.W_ih0 + (size_t)(512 + o) * 1024 + k)
                                           : *(const float4*)(a.W_hh0 + (size_t)(512 + o) * 512 + k - 1024);
          else if (gt == 2) { if (k < 1024)  v = *(const float4*)(a.W_ih0 + (size_t)(1024 + o) * 1024 + k); }
          else              { if (k >= 1024) v = *(const float4*)(a.W_hh0 + (size_t)(1024 + o) * 512 + k - 1024); }
        } else {                               // Wg1p [2048=4o+g][1024]
          int e2 = e - 3932160; int row = e2 >> 10, k = e2 & 1023;
          int o = row >> 2, gt = row & 3;
          if (gt == 0)      v = (k < 512) ? *(const float4*)(a.W_ih1 + (size_t)o * 512 + k)
                                          : *(const float4*)(a.W_hh1 + (size_t)o * 512 + k - 512);
          else if (gt == 1) v = (k < 512) ? *(const float4*)(a.W_ih1 + (size_t)(512 + o) * 512 + k)
                                          : *(const float4*)(a.W_hh1 + (size_t)(512 + o) * 512 + k - 512);
          else if (gt == 2) { if (k < 512)  v = *(const float4*)(a.W_ih1 + (size_t)(1024 + o) * 512 + k); }
          else              { if (k >= 512) v = *(const float4*)(a.W_hh1 + (size_t)(1024 + o) * 512 + k - 512); }
        }
        ushort4 u;
        u.x = f2bf(v.x); u.y = f2bf(v.y); u.z = f2bf(v.z); u.w = f2bf(v.w);
        *(ushort4*)(a.arena + e) = u;
      } else {
        int i2 = i - ARENA_Q;
        if (i2 < 1024) {                       // biases, 4o+g quads
          int r4 = i2 * 4; int layer = r4 >> 11; int r = r4 & 2047; int o = r >> 2;
          const float* bi = layer ? a.b_ih1 : a.b_ih0;
          const float* bh = layer ? a.b_hh1 : a.b_hh0;
          float4 v;
          v.x = bi[o] + bh[o];
          v.y = bi[512 + o] + bh[512 + o];
          v.z = bi[1024 + o];
          v.w = bh[1024 + o];
          *(float4*)((layer ? a.biasg1 : a.biasg0) + r) = v;
        } else if (i2 < 1024 + 16384) {        // emb gather
          int j = (i2 - 1024) * 4; int b = j >> 9, i0 = j & 511;
          float4 v = *(const float4*)(a.wdv + (size_t)b * (Vdim * Hdim) + (size_t)a.ids[b] * 512 + i0);
          ushort4 u;
          u.x = f2bf(v.x); u.y = f2bf(v.y); u.z = f2bf(v.z); u.w = f2bf(v.w);
          *(ushort4*)(a.X0bf + b * 1536 + i0) = u;
        } else if (i2 < 1024 + 32768) {        // lh0 -> X0bf[:,1024:]
          int j = (i2 - 1024 - 16384) * 4; int b = j >> 9, i0 = j & 511;
          float4 v = *(const float4*)(a.lh + (size_t)b * 512 + i0);
          ushort4 u;
          u.x = f2bf(v.x); u.y = f2bf(v.y); u.z = f2bf(v.z); u.w = f2bf(v.w);
          *(ushort4*)(a.X0bf + b * 1536 + 1024 + i0) = u;
        } else {                               // q -> X1bf[:,512:]
          int j = (i2 - 1024 - 32768) * 4; int b = j >> 9, i0 = j & 511;
          float4 v = *(const float4*)(a.lh + 65536 + (size_t)b * 512 + i0);
          ushort4 u;
          u.x = f2bf(v.x); u.y = f2bf(v.y); u.z = f2bf(v.z); u.w = f2bf(v.w);
          *(ushort4*)(a.X1bf + b * 1024 + 512 + i0) = u;
        }
      }
    }
  } else {                                     // blk 255: mask dtype detect
    int* sfp = (int*)smem;
    if (t == 0) *sfp = 0;
    __syncthreads();
    const uint32_t* m32 = (const uint32_t*)a.mask;
    int found = 0;
    for (int i = t; i < 16384; i += 512)
      if (m32[i] & 0xffffff00u) found = 1;     // nonzero byte at pos%4!=0 => byte mask
    if (found) *sfp = 1;
    __syncthreads();
    if (t == 0) *a.flag = *sfp;
  }
  gridg.sync();

  // ================= S2: attention energies -> scores =================
  {
    u16* As = (u16*)smem;                      // [128][40]
    u16* Bs = (u16*)(smem + 10240);            // [512][40]
    float* part = (float*)(smem + 51200);      // [8][128]
    const int arow = t >> 2;                   // 0..127 (= b)
    const int aks = (t & 3) * 8;
    const int bo = t >> 2;                     // B: o_i = bo + i*128
    const int bks = (t & 3) * 8;

    for (int l = blk; l < 512; l += 256) {
      f32x4 acc[8][4];
#pragma unroll
      for (int i = 0; i < 8; ++i)
#pragma unroll
        for (int j = 0; j < 4; ++j) acc[i][j] = (f32x4){0.f, 0.f, 0.f, 0.f};

      const float* abase = a.enc + ((size_t)l * 128 + arow) * 512 + aks;
      float4 ra0 = *(const float4*)(abase);
      float4 ra1 = *(const float4*)(abase + 4);
      uint4 rb[4];
#pragma unroll
      for (int i = 0; i < 4; ++i)
        rb[i] = *(const uint4*)(a.arena + (size_t)(bo + i * 128) * 512 + bks);

#pragma unroll
      for (int step = 0; step < 16; ++step) {
        __syncthreads();
        uint4 ap;
        ap.x = pk2(ra0.x, ra0.y); ap.y = pk2(ra0.z, ra0.w);
        ap.z = pk2(ra1.x, ra1.y); ap.w = pk2(ra1.z, ra1.w);
        *(uint4*)(As + arow * 40 + aks) = ap;
#pragma unroll
        for (int i = 0; i < 4; ++i)
          *(uint4*)(Bs + (bo + i * 128) * 40 + bks) = rb[i];
        if (step < 15) {
          int kt = (step + 1) * 32;
          ra0 = *(const float4*)(abase + kt);
          ra1 = *(const float4*)(abase + kt + 4);
#pragma unroll
          for (int i = 0; i < 4; ++i)
            rb[i] = *(const uint4*)(a.arena + (size_t)(bo + i * 128) * 512 + kt + bks);
        }
        __syncthreads();
        bf16x8 bfr[4];
#pragma unroll
        for (int ni = 0; ni < 4; ++ni)
          bfr[ni] = *(const bf16x8*)(Bs + (wid * 64 + ni * 16 + fr) * 40 + kof);
#pragma unroll
        for (int mi = 0; mi < 8; ++mi) {
          bf16x8 av = *(const bf16x8*)(As + (mi * 16 + fr) * 40 + kof);
#pragma unroll
          for (int ni = 0; ni < 4; ++ni)
            acc[mi][ni] = __builtin_amdgcn_mfma_f32_16x16x32_bf16(av, bfr[ni], acc[mi][ni], 0, 0, 0);
        }
      }
      // epilogue: +qW, tanh, *scW, reduce over o
#pragma unroll
      for (int mi = 0; mi < 8; ++mi) {
        float rs0 = 0.f, rs1 = 0.f, rs2 = 0.f, rs3 = 0.f;
#pragma unroll
        for (int ni = 0; ni < 4; ++ni) {
          int o = wid * 64 + ni * 16 + fr;
          float sw = a.scW[o];
          int brow = mi * 16 + g * 4;
          rs0 += sw * fast_tanh(acc[mi][ni][0] + a.qW[(size_t)(brow + 0) * 512 + o]);
          rs1 += sw * fast_tanh(acc[mi][ni][1] + a.qW[(size_t)(brow + 1) * 512 + o]);
          rs2 += sw * fast_tanh(acc[mi][ni][2] + a.qW[(size_t)(brow + 2) * 512 + o]);
          rs3 += sw * fast_tanh(acc[mi][ni][3] + a.qW[(size_t)(brow + 3) * 512 + o]);
        }
#pragma unroll
        for (int d = 1; d < 16; d <<= 1) {
          rs0 += __shfl_xor(rs0, d);
          rs1 += __shfl_xor(rs1, d);
          rs2 += __shfl_xor(rs2, d);
          rs3 += __shfl_xor(rs3, d);
        }
        if (fr < 4) {
          float v = (fr == 0) ? rs0 : (fr == 1) ? rs1 : (fr == 2) ? rs2 : rs3;
          part[wid * 128 + mi * 16 + g * 4 + fr] = v;
        }
      }
      __syncthreads();
      if (t < 128) {
        float s = 0.f;
#pragma unroll
        for (int w2 = 0; w2 < 8; ++w2) s += part[w2 * 128 + t];
        a.scores[(size_t)t * 512 + l] = s;
      }
      __syncthreads();
    }
  }
  gridg.sync();

  // ================= S3: mask + softmax + context =================
  {
    float* wgt  = (float*)smem;                // 512
    float* redm = wgt + 512;                   // 8
    float* reds = redm + 8;                    // 8
    float* ps   = (float*)(smem + 4096);       // [4][128][2]
    int b = blk >> 1, ch = blk & 1;
    float s = a.scores[(size_t)b * 512 + t];
    bool isbyte = (*a.flag != 0);
    bool m = isbyte ? (((const uint8_t*)a.mask)[b * 512 + t] != 0)
                    : (((const int*)a.mask)[b * 512 + t] != 0);
    float v = m ? -1e12f : s;
    float mx = v;
#pragma unroll
    for (int d = 1; d < 64; d <<= 1) mx = fmaxf(mx, __shfl_xor(mx, d));
    if (lane == 0) redm[wid] = mx;
    __syncthreads();
    mx = redm[0];
#pragma unroll
    for (int w2 = 1; w2 < 8; ++w2) mx = fmaxf(mx, redm[w2]);
    float e = __expf(v - mx);
    float sm = e;
#pragma unroll
    for (int d = 1; d < 64; d <<= 1) sm += __shfl_xor(sm, d);
    if (lane == 0) reds[wid] = sm;
    __syncthreads();
    sm = reds[0] + reds[1] + reds[2] + reds[3] + reds[4] + reds[5] + reds[6] + reds[7];
    wgt[t] = e / sm;
    __syncthreads();
    int cp = t & 127, lq = t >> 7;
    int col = ch * 256 + cp * 2;
    float a0 = 0.f, a1 = 0.f;
    for (int l = lq * 128; l < lq * 128 + 128; ++l) {
      float wl = wgt[l];
      if (wl != 0.0f) {
        float2 ev = *(const float2*)(a.enc + ((size_t)l * 128 + b) * 512 + col);
        a0 += wl * ev.x;
        a1 += wl * ev.y;
      }
    }
    ps[(lq * 128 + cp) * 2 + 0] = a0;
    ps[(lq * 128 + cp) * 2 + 1] = a1;
    __syncthreads();
    if (t < 128) {
      float r0 = ps[t * 2] + ps[(128 + t) * 2] + ps[(256 + t) * 2] + ps[(384 + t) * 2];
      float r1 = ps[t * 2 + 1] + ps[(128 + t) * 2 + 1] + ps[(256 + t) * 2 + 1] + ps[(384 + t) * 2 + 1];
      uint32_t packed = pk2(r0, r1);
      int cc = ch * 256 + t * 2;
      *(uint32_t*)(a.X0bf + b * 1536 + 512 + cc) = packed;
      *(uint32_t*)(a.c1bf + b * 1024 + 512 + cc) = packed;
    }
  }
  gridg.sync();

  // ================= S4: GRU layer 0 =================
  if (blk < 128)
    gru_stage(a, a.X0bf, 1536, a.arena + 786432, a.biasg0, a.lh, a.h0o, a.X1bf,
              1536, blk, t, (float*)smem);
  gridg.sync();

  // ================= S5: GRU layer 1 =================
  if (blk < 128)
    gru_stage(a, a.X1bf, 1024, a.arena + 3932160, a.biasg1, a.lh + 65536, a.h1o, a.c1bf,
              1024, blk, t, (float*)smem);
  gridg.sync();

  // ================= S6: output = tanh(c1 @ Wcat^T + cat_b) =================
  if (blk < 32) {
    int wv = wid;
    int n0 = blk * 16;
    f32x4 acc = {0.f, 0.f, 0.f, 0.f};
    const u16* Xr = a.c1bf + (size_t)(wv * 16 + fr) * 1024;
    const u16* Wr = a.arena + 262144 + (size_t)(n0 + fr) * 1024;
#pragma unroll 4
    for (int kt = 0; kt < 1024; kt += 32) {
      bf16x8 av = *(const bf16x8*)(Xr + kt + kof);
      bf16x8 bv = *(const bf16x8*)(Wr + kt + kof);
      acc = __builtin_amdgcn_mfma_f32_16x16x32_bf16(av, bv, acc, 0, 0, 0);
    }
    float vb = a.cat_b[n0 + fr];
#pragma unroll
    for (int j = 0; j < 4; ++j)
      a.out[(size_t)(wv * 16 + g * 4 + j) * 512 + n0 + fr] = tanhf(acc[j] + vb);
  }
}

extern "C" void kernel_launch(void* const* d_in, const int* in_sizes, int n_in,
                              void* d_out, int out_size, void* d_ws, size_t ws_size,
                              hipStream_t stream) {
  float* out = (float*)d_out;

  float* ws     = (float*)d_ws;
  float* qW     = ws;                        // 65536
  float* scores = ws + 65536;                // 65536
  float* biasg0 = ws + 131072;               // 2048
  float* biasg1 = ws + 133120;               // 2048
  int*   flag   = (int*)(ws + 135168);       // 16
  u16*   arena  = (u16*)(ws + 135184);       // 6029312 u16 = 3014656 f
  u16*   X0bf   = (u16*)(ws + 3149840);      // 196608 u16
  u16*   X1bf   = (u16*)(ws + 3248144);      // 131072 u16
  u16*   c1bf   = (u16*)(ws + 3313680);      // 131072 u16

  KArgs ka;
  ka.ids    = (const int*)  d_in[0];
  ka.lh     = (const float*)d_in[1];
  ka.wdv    = (const float*)d_in[2];
  ka.enc    = (const float*)d_in[3];
  ka.mask   = d_in[4];
  ka.attn_W = (const float*)d_in[5];
  ka.attn_b = (const float*)d_in[6];
  ka.scW    = (const float*)d_in[7];
  ka.cat_W  = (const float*)d_in[8];
  ka.cat_b  = (const float*)d_in[9];
  ka.W_ih0  = (const float*)d_in[10];
  ka.W_hh0  = (const float*)d_in[11];
  ka.b_ih0  = (const float*)d_in[12];
  ka.b_hh0  = (const float*)d_in[13];
  ka.W_ih1  = (const float*)d_in[14];
  ka.W_hh1  = (const float*)d_in[15];
  ka.b_ih1  = (const float*)d_in[16];
  ka.b_hh1  = (const float*)d_in[17];
  ka.out = out; ka.h0o = out + 65536; ka.h1o = out + 131072;
  ka.qW = qW; ka.scores = scores; ka.biasg0 = biasg0; ka.biasg1 = biasg1;
  ka.flag = flag; ka.arena = arena; ka.X0bf = X0bf; ka.X1bf = X1bf; ka.c1bf = c1bf;

  void* params[] = { (void*)&ka };
  hipLaunchCooperativeKernel((const void*)mega_kernel, dim3(256), dim3(512),
                             params, SMEM_BYTES, stream);
}

// Round 6
// 667.832 us; speedup vs baseline: 1.0066x; 1.0066x over previous
//
#include <hip/hip_runtime.h>
#include <hip/hip_cooperative_groups.h>
#include <stdint.h>

namespace cg = cooperative_groups;

#define Hdim 512
#define Bdim 128
#define Ldim 512
#define Vdim 2048

typedef unsigned short u16;
using f32x4  = float  __attribute__((ext_vector_type(4)));
using bf16x8 = __bf16 __attribute__((ext_vector_type(8)));

__device__ inline u16 f2bf(float x) {
  uint32_t u = __float_as_uint(x);
  u += 0x7fffu + ((u >> 16) & 1u);   // RNE
  return (u16)(u >> 16);
}
__device__ inline uint32_t pk2(float lo, float hi) {
  return (uint32_t)f2bf(lo) | ((uint32_t)f2bf(hi) << 16);
}
__device__ inline float fast_tanh(float x) {
  return 1.0f - 2.0f / (__expf(2.0f * x) + 1.0f);
}
__device__ inline float fast_sig(float x) { return 1.0f / (1.0f + __expf(-x)); }

__device__ inline bf16x8 pack_bf8(float4 x, float4 y) {
  union { uint32_t d[4]; bf16x8 v; } r;
  r.d[0] = pk2(x.x, x.y); r.d[1] = pk2(x.z, x.w);
  r.d[2] = pk2(y.x, y.y); r.d[3] = pk2(y.z, y.w);
  return r.v;
}

struct KArgs {
  const int* ids; const float* lh; const float* wdv; const float* enc;
  const void* mask; const float* attn_W; const float* attn_b; const float* scW;
  const float* cat_W; const float* cat_b;
  const float* W_ih0; const float* W_hh0; const float* b_ih0; const float* b_hh0;
  const float* W_ih1; const float* W_hh1; const float* b_ih1; const float* b_hh1;
  float* out; float* h0o; float* h1o;
  float* qW; float* scores; float* biasg0; float* biasg1; int* flag;
  u16* arena; u16* X0bf; u16* X1bf; u16* c1bf;
};

// LDS budget: attn stage is max: As 128x40 u16 (10240B) + Bs 512x40 u16 (40960B)
// + part 8x128 f32 (4096B) = 55296B
#define SMEM_BYTES 55296

// GRU GEMM: M=128, 16 gate-cols per block (gate-interleaved 4o+g), fused combine.
__device__ inline void gru_stage(const KArgs& a, const u16* X, int ldx, const u16* Wp,
                                 const float* biasg, const float* hprev,
                                 float* hout, u16* xdst, int K,
                                 int blk, int t, float* ctile) {
  int lane = t & 63, wv = t >> 6, fr = lane & 15, g = lane >> 4, kof = g * 8;
  int n0 = blk * 16;
  f32x4 acc = {0.f, 0.f, 0.f, 0.f};
  const u16* Xr = X + (size_t)(wv * 16 + fr) * ldx;
  const u16* Wr = Wp + (size_t)(n0 + fr) * K;
#pragma unroll 4
  for (int kt = 0; kt < K; kt += 32) {
    bf16x8 av = *(const bf16x8*)(Xr + kt + kof);
    bf16x8 bv = *(const bf16x8*)(Wr + kt + kof);
    acc = __builtin_amdgcn_mfma_f32_16x16x32_bf16(av, bv, acc, 0, 0, 0);
  }
  float vb = biasg[n0 + fr];
#pragma unroll
  for (int j = 0; j < 4; ++j)
    ctile[(wv * 16 + g * 4 + j) * 20 + fr] = acc[j] + vb;
  __syncthreads();
  {
    int b2 = t >> 2, oj = t & 3;
    float cr  = ctile[b2 * 20 + oj * 4 + 0];
    float cz  = ctile[b2 * 20 + oj * 4 + 1];
    float ci  = ctile[b2 * 20 + oj * 4 + 2];
    float chh = ctile[b2 * 20 + oj * 4 + 3];
    int o = blk * 4 + oj;
    float r = fast_sig(cr), z = fast_sig(cz);
    float n = tanhf(ci + r * chh);
    float h = (1.0f - z) * n + z * hprev[b2 * 512 + o];
    hout[b2 * 512 + o] = h;
    xdst[b2 * 1024 + o] = f2bf(h);
  }
}

__global__ __launch_bounds__(512) void mega_kernel(KArgs a) {
  extern __shared__ __align__(16) unsigned char smem[];
  cg::grid_group gridg = cg::this_grid();
  const int blk = blockIdx.x, t = threadIdx.x;
  const int lane = t & 63, wid = t >> 6;
  const int fr = lane & 15, g = lane >> 4, kof = g * 8;

  // ================= Phase A: prep + qW =================
  if (blk < 16) {
    // qW = q @ attn_W[:, :512]^T + attn_b   (f32 inputs, in-reg bf16 cvt)
    int mh = wid & 3, nh = wid >> 2;
    int n0 = blk * 32 + nh * 16;
    int rb0 = mh * 32;
    f32x4 ac0 = {0.f, 0.f, 0.f, 0.f}, ac1 = {0.f, 0.f, 0.f, 0.f};
    const float* q = a.lh + 65536;
#pragma unroll 2
    for (int kt = 0; kt < 512; kt += 32) {
      const float* qr0 = q + (size_t)(rb0 + fr) * 512 + kt + kof;
      const float* qr1 = qr0 + 16 * 512;
      const float* wr  = a.attn_W + (size_t)(n0 + fr) * 1024 + kt + kof;
      float4 x0 = *(const float4*)qr0, x1 = *(const float4*)(qr0 + 4);
      float4 y0 = *(const float4*)qr1, y1 = *(const float4*)(qr1 + 4);
      float4 w0 = *(const float4*)wr,  w1 = *(const float4*)(wr + 4);
      bf16x8 A0 = pack_bf8(x0, x1), A1 = pack_bf8(y0, y1), Bb = pack_bf8(w0, w1);
      ac0 = __builtin_amdgcn_mfma_f32_16x16x32_bf16(A0, Bb, ac0, 0, 0, 0);
      ac1 = __builtin_amdgcn_mfma_f32_16x16x32_bf16(A1, Bb, ac1, 0, 0, 0);
    }
    float vb = a.attn_b[n0 + fr];
#pragma unroll
    for (int j = 0; j < 4; ++j) {
      a.qW[(size_t)(rb0 + g * 4 + j) * 512 + n0 + fr]      = ac0[j] + vb;
      a.qW[(size_t)(rb0 + 16 + g * 4 + j) * 512 + n0 + fr] = ac1[j] + vb;
    }
  } else if (blk < 255) {
    const int NT = 239 * 512;
    const int ARENA_Q = 1507328;
    const int T_TOTAL = ARENA_Q + 1024 + 3 * 16384;
    int tid = (blk - 16) * 512 + t;
    for (int i = tid; i < T_TOTAL; i += NT) {
      if (i < ARENA_Q) {
        int e = i * 4;
        float4 v = {0.f, 0.f, 0.f, 0.f};
        if (e < 262144) {                      // Wenc = attn_W[:, 512:]
          int o = e >> 9, k = e & 511;
          v = *(const float4*)(a.attn_W + (size_t)o * 1024 + 512 + k);
        } else if (e < 786432) {               // Wcat
          int e2 = e - 262144; int o = e2 >> 10, k = e2 & 1023;
          v = *(const float4*)(a.cat_W + (size_t)o * 1024 + k);
        } else if (e < 3932160) {              // Wg0p [2048=4o+g][1536]
          int e2 = e - 786432; int row = e2 / 1536, k = e2 % 1536;
          int o = row >> 2, gt = row & 3;
          if (gt == 0)      v = (k < 1024) ? *(const float4*)(a.W_ih0 + (size_t)o * 1024 + k)
                                           : *(const float4*)(a.W_hh0 + (size_t)o * 512 + k - 1024);
          else if (gt == 1) v = (k < 1024) ? *(const float4*)(a.W_ih0 + (size_t)(512 + o) * 1024 + k)
                                           : *(const float4*)(a.W_hh0 + (size_t)(512 + o) * 512 + k - 1024);
          else if (gt == 2) { if (k < 1024)  v = *(const float4*)(a.W_ih0 + (size_t)(1024 + o) * 1024 + k); }
          else              { if (k >= 1024) v = *(const float4*)(a.W_hh0 + (size_t)(1024 + o) * 512 + k - 1024); }
        } else {                               // Wg1p [2048=4o+g][1024]
          int e2 = e - 3932160; int row = e2 >> 10, k = e2 & 1023;
          int o = row >> 2, gt = row & 3;
          if (gt == 0)      v = (k < 512) ? *(const float4*)(a.W_ih1 + (size_t)o * 512 + k)
                                          : *(const float4*)(a.W_hh1 + (size_t)o * 512 + k - 512);
          else if (gt == 1) v = (k < 512) ? *(const float4*)(a.W_ih1 + (size_t)(512 + o) * 512 + k)
                                          : *(const float4*)(a.W_hh1 + (size_t)(512 + o) * 512 + k - 512);
          else if (gt == 2) { if (k < 512)  v = *(const float4*)(a.W_ih1 + (size_t)(1024 + o) * 512 + k); }
          else              { if (k >= 512) v = *(const float4*)(a.W_hh1 + (size_t)(1024 + o) * 512 + k - 512); }
        }
        ushort4 u;
        u.x = f2bf(v.x); u.y = f2bf(v.y); u.z = f2bf(v.z); u.w = f2bf(v.w);
        *(ushort4*)(a.arena + e) = u;
      } else {
        int i2 = i - ARENA_Q;
        if (i2 < 1024) {                       // biases, 4o+g quads
          int r4 = i2 * 4; int layer = r4 >> 11; int r = r4 & 2047; int o = r >> 2;
          const float* bi = layer ? a.b_ih1 : a.b_ih0;
          const float* bh = layer ? a.b_hh1 : a.b_hh0;
          float4 v;
          v.x = bi[o] + bh[o];
          v.y = bi[512 + o] + bh[512 + o];
          v.z = bi[1024 + o];
          v.w = bh[1024 + o];
          *(float4*)((layer ? a.biasg1 : a.biasg0) + r) = v;
        } else if (i2 < 1024 + 16384) {        // emb gather
          int j = (i2 - 1024) * 4; int b = j >> 9, i0 = j & 511;
          float4 v = *(const float4*)(a.wdv + (size_t)b * (Vdim * Hdim) + (size_t)a.ids[b] * 512 + i0);
          ushort4 u;
          u.x = f2bf(v.x); u.y = f2bf(v.y); u.z = f2bf(v.z); u.w = f2bf(v.w);
          *(ushort4*)(a.X0bf + b * 1536 + i0) = u;
        } else if (i2 < 1024 + 32768) {        // lh0 -> X0bf[:,1024:]
          int j = (i2 - 1024 - 16384) * 4; int b = j >> 9, i0 = j & 511;
          float4 v = *(const float4*)(a.lh + (size_t)b * 512 + i0);
          ushort4 u;
          u.x = f2bf(v.x); u.y = f2bf(v.y); u.z = f2bf(v.z); u.w = f2bf(v.w);
          *(ushort4*)(a.X0bf + b * 1536 + 1024 + i0) = u;
        } else {                               // q -> X1bf[:,512:]
          int j = (i2 - 1024 - 32768) * 4; int b = j >> 9, i0 = j & 511;
          float4 v = *(const float4*)(a.lh + 65536 + (size_t)b * 512 + i0);
          ushort4 u;
          u.x = f2bf(v.x); u.y = f2bf(v.y); u.z = f2bf(v.z); u.w = f2bf(v.w);
          *(ushort4*)(a.X1bf + b * 1024 + 512 + i0) = u;
        }
      }
    }
  } else {                                     // blk 255: mask dtype detect
    int* sfp = (int*)smem;
    if (t == 0) *sfp = 0;
    __syncthreads();
    const uint32_t* m32 = (const uint32_t*)a.mask;
    int found = 0;
    for (int i = t; i < 16384; i += 512)
      if (m32[i] & 0xffffff00u) found = 1;     // nonzero byte at pos%4!=0 => byte mask
    if (found) *sfp = 1;
    __syncthreads();
    if (t == 0) *a.flag = *sfp;
  }
  gridg.sync();

  // ================= S2: attention energies -> scores =================
  {
    u16* As = (u16*)smem;                      // [128][40]
    u16* Bs = (u16*)(smem + 10240);            // [512][40]
    float* part = (float*)(smem + 51200);      // [8][128]
    const int arow = t >> 2;                   // 0..127 (= b)
    const int aks = (t & 3) * 8;
    const int bo = t >> 2;                     // B: o_i = bo + i*128
    const int bks = (t & 3) * 8;

    for (int l = blk; l < 512; l += 256) {
      f32x4 acc[8][4];
#pragma unroll
      for (int i = 0; i < 8; ++i)
#pragma unroll
        for (int j = 0; j < 4; ++j) acc[i][j] = (f32x4){0.f, 0.f, 0.f, 0.f};

      const float* abase = a.enc + ((size_t)l * 128 + arow) * 512 + aks;
      float4 ra0 = *(const float4*)(abase);
      float4 ra1 = *(const float4*)(abase + 4);
      uint4 rb[4];
#pragma unroll
      for (int i = 0; i < 4; ++i)
        rb[i] = *(const uint4*)(a.arena + (size_t)(bo + i * 128) * 512 + bks);

#pragma unroll
      for (int step = 0; step < 16; ++step) {
        __syncthreads();
        uint4 ap;
        ap.x = pk2(ra0.x, ra0.y); ap.y = pk2(ra0.z, ra0.w);
        ap.z = pk2(ra1.x, ra1.y); ap.w = pk2(ra1.z, ra1.w);
        *(uint4*)(As + arow * 40 + aks) = ap;
#pragma unroll
        for (int i = 0; i < 4; ++i)
          *(uint4*)(Bs + (bo + i * 128) * 40 + bks) = rb[i];
        if (step < 15) {
          int kt = (step + 1) * 32;
          ra0 = *(const float4*)(abase + kt);
          ra1 = *(const float4*)(abase + kt + 4);
#pragma unroll
          for (int i = 0; i < 4; ++i)
            rb[i] = *(const uint4*)(a.arena + (size_t)(bo + i * 128) * 512 + kt + bks);
        }
        __syncthreads();
        bf16x8 bfr[4];
#pragma unroll
        for (int ni = 0; ni < 4; ++ni)
          bfr[ni] = *(const bf16x8*)(Bs + (wid * 64 + ni * 16 + fr) * 40 + kof);
#pragma unroll
        for (int mi = 0; mi < 8; ++mi) {
          bf16x8 av = *(const bf16x8*)(As + (mi * 16 + fr) * 40 + kof);
#pragma unroll
          for (int ni = 0; ni < 4; ++ni)
            acc[mi][ni] = __builtin_amdgcn_mfma_f32_16x16x32_bf16(av, bfr[ni], acc[mi][ni], 0, 0, 0);
        }
      }
      // epilogue: +qW, tanh, *scW, reduce over o
#pragma unroll
      for (int mi = 0; mi < 8; ++mi) {
        float rs0 = 0.f, rs1 = 0.f, rs2 = 0.f, rs3 = 0.f;
#pragma unroll
        for (int ni = 0; ni < 4; ++ni) {
          int o = wid * 64 + ni * 16 + fr;
          float sw = a.scW[o];
          int brow = mi * 16 + g * 4;
          rs0 += sw * fast_tanh(acc[mi][ni][0] + a.qW[(size_t)(brow + 0) * 512 + o]);
          rs1 += sw * fast_tanh(acc[mi][ni][1] + a.qW[(size_t)(brow + 1) * 512 + o]);
          rs2 += sw * fast_tanh(acc[mi][ni][2] + a.qW[(size_t)(brow + 2) * 512 + o]);
          rs3 += sw * fast_tanh(acc[mi][ni][3] + a.qW[(size_t)(brow + 3) * 512 + o]);
        }
#pragma unroll
        for (int d = 1; d < 16; d <<= 1) {
          rs0 += __shfl_xor(rs0, d);
          rs1 += __shfl_xor(rs1, d);
          rs2 += __shfl_xor(rs2, d);
          rs3 += __shfl_xor(rs3, d);
        }
        if (fr < 4) {
          float v = (fr == 0) ? rs0 : (fr == 1) ? rs1 : (fr == 2) ? rs2 : rs3;
          part[wid * 128 + mi * 16 + g * 4 + fr] = v;
        }
      }
      __syncthreads();
      if (t < 128) {
        float s = 0.f;
#pragma unroll
        for (int w2 = 0; w2 < 8; ++w2) s += part[w2 * 128 + t];
        a.scores[(size_t)t * 512 + l] = s;
      }
      __syncthreads();
    }
  }
  gridg.sync();

  // ================= S3: mask + softmax + context =================
  {
    float* wgt  = (float*)smem;                // 512
    float* redm = wgt + 512;                   // 8
    float* reds = redm + 8;                    // 8
    float* ps   = (float*)(smem + 4096);       // [4][128][2]
    int b = blk >> 1, ch = blk & 1;
    float s = a.scores[(size_t)b * 512 + t];
    bool isbyte = (*a.flag != 0);
    bool m = isbyte ? (((const uint8_t*)a.mask)[b * 512 + t] != 0)
                    : (((const int*)a.mask)[b * 512 + t] != 0);
    float v = m ? -1e12f : s;
    float mx = v;
#pragma unroll
    for (int d = 1; d < 64; d <<= 1) mx = fmaxf(mx, __shfl_xor(mx, d));
    if (lane == 0) redm[wid] = mx;
    __syncthreads();
    mx = redm[0];
#pragma unroll
    for (int w2 = 1; w2 < 8; ++w2) mx = fmaxf(mx, redm[w2]);
    float e = __expf(v - mx);
    float sm = e;
#pragma unroll
    for (int d = 1; d < 64; d <<= 1) sm += __shfl_xor(sm, d);
    if (lane == 0) reds[wid] = sm;
    __syncthreads();
    sm = reds[0] + reds[1] + reds[2] + reds[3] + reds[4] + reds[5] + reds[6] + reds[7];
    wgt[t] = e / sm;
    __syncthreads();
    int cp = t & 127, lq = t >> 7;
    int col = ch * 256 + cp * 2;
    float a0 = 0.f, a1 = 0.f;
    for (int l = lq * 128; l < lq * 128 + 128; ++l) {
      float wl = wgt[l];
      if (wl != 0.0f) {
        float2 ev = *(const float2*)(a.enc + ((size_t)l * 128 + b) * 512 + col);
        a0 += wl * ev.x;
        a1 += wl * ev.y;
      }
    }
    ps[(lq * 128 + cp) * 2 + 0] = a0;
    ps[(lq * 128 + cp) * 2 + 1] = a1;
    __syncthreads();
    if (t < 128) {
      float r0 = ps[t * 2] + ps[(128 + t) * 2] + ps[(256 + t) * 2] + ps[(384 + t) * 2];
      float r1 = ps[t * 2 + 1] + ps[(128 + t) * 2 + 1] + ps[(256 + t) * 2 + 1] + ps[(384 + t) * 2 + 1];
      uint32_t packed = pk2(r0, r1);
      int cc = ch * 256 + t * 2;
      *(uint32_t*)(a.X0bf + b * 1536 + 512 + cc) = packed;
      *(uint32_t*)(a.c1bf + b * 1024 + 512 + cc) = packed;
    }
  }
  gridg.sync();

  // ================= S4: GRU layer 0 =================
  if (blk < 128)
    gru_stage(a, a.X0bf, 1536, a.arena + 786432, a.biasg0, a.lh, a.h0o, a.X1bf,
              1536, blk, t, (float*)smem);
  gridg.sync();

  // ================= S5: GRU layer 1 =================
  if (blk < 128)
    gru_stage(a, a.X1bf, 1024, a.arena + 3932160, a.biasg1, a.lh + 65536, a.h1o, a.c1bf,
              1024, blk, t, (float*)smem);
  gridg.sync();

  // ================= S6: output = tanh(c1 @ Wcat^T + cat_b) =================
  if (blk < 32) {
    int wv = wid;
    int n0 = blk * 16;
    f32x4 acc = {0.f, 0.f, 0.f, 0.f};
    const u16* Xr = a.c1bf + (size_t)(wv * 16 + fr) * 1024;
    const u16* Wr = a.arena + 262144 + (size_t)(n0 + fr) * 1024;
#pragma unroll 4
    for (int kt = 0; kt < 1024; kt += 32) {
      bf16x8 av = *(const bf16x8*)(Xr + kt + kof);
      bf16x8 bv = *(const bf16x8*)(Wr + kt + kof);
      acc = __builtin_amdgcn_mfma_f32_16x16x32_bf16(av, bv, acc, 0, 0, 0);
    }
    float vb = a.cat_b[n0 + fr];
#pragma unroll
    for (int j = 0; j < 4; ++j)
      a.out[(size_t)(wv * 16 + g * 4 + j) * 512 + n0 + fr] = tanhf(acc[j] + vb);
  }
}

extern "C" void kernel_launch(void* const* d_in, const int* in_sizes, int n_in,
                              void* d_out, int out_size, void* d_ws, size_t ws_size,
                              hipStream_t stream) {
  float* out = (float*)d_out;

  float* ws     = (float*)d_ws;
  float* qW     = ws;                        // 65536
  float* scores = ws + 65536;                // 65536
  float* biasg0 = ws + 131072;               // 2048
  float* biasg1 = ws + 133120;               // 2048
  int*   flag   = (int*)(ws + 135168);       // 16
  u16*   arena  = (u16*)(ws + 135184);       // 6029312 u16 = 3014656 f
  u16*   X0bf   = (u16*)(ws + 3149840);      // 196608 u16
  u16*   X1bf   = (u16*)(ws + 3248144);      // 131072 u16
  u16*   c1bf   = (u16*)(ws + 3313680);      // 131072 u16

  KArgs ka;
  ka.ids    = (const int*)  d_in[0];
  ka.lh     = (const float*)d_in[1];
  ka.wdv    = (const float*)d_in[2];
  ka.enc    = (const float*)d_in[3];
  ka.mask   = d_in[4];
  ka.attn_W = (const float*)d_in[5];
  ka.attn_b = (const float*)d_in[6];
  ka.scW    = (const float*)d_in[7];
  ka.cat_W  = (const float*)d_in[8];
  ka.cat_b  = (const float*)d_in[9];
  ka.W_ih0  = (const float*)d_in[10];
  ka.W_hh0  = (const float*)d_in[11];
  ka.b_ih0  = (const float*)d_in[12];
  ka.b_hh0  = (const float*)d_in[13];
  ka.W_ih1  = (const float*)d_in[14];
  ka.W_hh1  = (const float*)d_in[15];
  ka.b_ih1  = (const float*)d_in[16];
  ka.b_hh1  = (const float*)d_in[17];
  ka.out = out; ka.h0o = out + 65536; ka.h1o = out + 131072;
  ka.qW = qW; ka.scores = scores; ka.biasg0 = biasg0; ka.biasg1 = biasg1;
  ka.flag = flag; ka.arena = arena; ka.X0bf = X0bf; ka.X1bf = X1bf; ka.c1bf = c1bf;

  void* params[] = { (void*)&ka };
  hipLaunchCooperativeKernel((const void*)mega_kernel, dim3(256), dim3(512),
                             params, SMEM_BYTES, stream);
}

// Round 7
// 368.359 us; speedup vs baseline: 1.8249x; 1.8130x over previous
//
#include <hip/hip_runtime.h>
#include <hip/hip_cooperative_groups.h>
#include <stdint.h>

namespace cg = cooperative_groups;

#define Hdim 512
#define Bdim 128
#define Ldim 512
#define Vdim 2048

typedef unsigned short u16;
using f32x4  = float  __attribute__((ext_vector_type(4)));
using bf16x8 = __bf16 __attribute__((ext_vector_type(8)));

__device__ inline u16 f2bf(float x) {
  uint32_t u = __float_as_uint(x);
  u += 0x7fffu + ((u >> 16) & 1u);   // RNE
  return (u16)(u >> 16);
}
__device__ inline uint32_t pk2(float lo, float hi) {
  return (uint32_t)f2bf(lo) | ((uint32_t)f2bf(hi) << 16);
}
__device__ inline float fast_tanh(float x) {
  return 1.0f - 2.0f / (__expf(2.0f * x) + 1.0f);
}
__device__ inline float fast_sig(float x) { return 1.0f / (1.0f + __expf(-x)); }

__device__ inline bf16x8 pack_bf8(float4 x, float4 y) {
  union { uint32_t d[4]; bf16x8 v; } r;
  r.d[0] = pk2(x.x, x.y); r.d[1] = pk2(x.z, x.w);
  r.d[2] = pk2(y.x, y.y); r.d[3] = pk2(y.z, y.w);
  return r.v;
}

struct KArgs {
  const int* ids; const float* lh; const float* wdv; const float* enc;
  const void* mask; const float* attn_W; const float* attn_b; const float* scW;
  const float* cat_W; const float* cat_b;
  const float* W_ih0; const float* W_hh0; const float* b_ih0; const float* b_hh0;
  const float* W_ih1; const float* W_hh1; const float* b_ih1; const float* b_hh1;
  float* out; float* h0o; float* h1o;
  float* qW; float* scores; float* biasg0; float* biasg1; int* flag;
  u16* arena; u16* X0bf; u16* X1bf; u16* c1bf;
};

// LDS: As 2x128x40 u16 (20480B) + Bs 2x256x40 u16 (40960B) + part 8x128 f32
// (4096B) + sacc 128 f32 (512B) = 66048B
#define SMEM_BYTES 66048

// GRU GEMM: M=128, 16 gate-cols per block (gate-interleaved 4o+g), fused combine.
__device__ inline void gru_stage(const KArgs& a, const u16* X, int ldx, const u16* Wp,
                                 const float* biasg, const float* hprev,
                                 float* hout, u16* xdst, int K,
                                 int blk, int t, float* ctile) {
  int lane = t & 63, wv = t >> 6, fr = lane & 15, g = lane >> 4, kof = g * 8;
  int n0 = blk * 16;
  f32x4 acc = {0.f, 0.f, 0.f, 0.f};
  const u16* Xr = X + (size_t)(wv * 16 + fr) * ldx;
  const u16* Wr = Wp + (size_t)(n0 + fr) * K;
#pragma unroll 4
  for (int kt = 0; kt < K; kt += 32) {
    bf16x8 av = *(const bf16x8*)(Xr + kt + kof);
    bf16x8 bv = *(const bf16x8*)(Wr + kt + kof);
    acc = __builtin_amdgcn_mfma_f32_16x16x32_bf16(av, bv, acc, 0, 0, 0);
  }
  float vb = biasg[n0 + fr];
#pragma unroll
  for (int j = 0; j < 4; ++j)
    ctile[(wv * 16 + g * 4 + j) * 20 + fr] = acc[j] + vb;
  __syncthreads();
  {
    int b2 = t >> 2, oj = t & 3;
    float cr  = ctile[b2 * 20 + oj * 4 + 0];
    float cz  = ctile[b2 * 20 + oj * 4 + 1];
    float ci  = ctile[b2 * 20 + oj * 4 + 2];
    float chh = ctile[b2 * 20 + oj * 4 + 3];
    int o = blk * 4 + oj;
    float r = fast_sig(cr), z = fast_sig(cz);
    float n = tanhf(ci + r * chh);
    float h = (1.0f - z) * n + z * hprev[b2 * 512 + o];
    hout[b2 * 512 + o] = h;
    xdst[b2 * 1024 + o] = f2bf(h);
  }
}

__global__ __launch_bounds__(512)
__attribute__((amdgpu_waves_per_eu(2, 2)))
void mega_kernel(KArgs a) {
  extern __shared__ __align__(16) unsigned char smem[];
  cg::grid_group gridg = cg::this_grid();
  const int blk = blockIdx.x, t = threadIdx.x;
  const int lane = t & 63, wid = t >> 6;
  const int fr = lane & 15, g = lane >> 4, kof = g * 8;

  // ================= Phase A: prep + qW =================
  if (blk < 16) {
    // qW = q @ attn_W[:, :512]^T + attn_b   (f32 inputs, in-reg bf16 cvt)
    int mh = wid & 3, nh = wid >> 2;
    int n0 = blk * 32 + nh * 16;
    int rb0 = mh * 32;
    f32x4 ac0 = {0.f, 0.f, 0.f, 0.f}, ac1 = {0.f, 0.f, 0.f, 0.f};
    const float* q = a.lh + 65536;
#pragma unroll 2
    for (int kt = 0; kt < 512; kt += 32) {
      const float* qr0 = q + (size_t)(rb0 + fr) * 512 + kt + kof;
      const float* qr1 = qr0 + 16 * 512;
      const float* wr  = a.attn_W + (size_t)(n0 + fr) * 1024 + kt + kof;
      float4 x0 = *(const float4*)qr0, x1 = *(const float4*)(qr0 + 4);
      float4 y0 = *(const float4*)qr1, y1 = *(const float4*)(qr1 + 4);
      float4 w0 = *(const float4*)wr,  w1 = *(const float4*)(wr + 4);
      bf16x8 A0 = pack_bf8(x0, x1), A1 = pack_bf8(y0, y1), Bb = pack_bf8(w0, w1);
      ac0 = __builtin_amdgcn_mfma_f32_16x16x32_bf16(A0, Bb, ac0, 0, 0, 0);
      ac1 = __builtin_amdgcn_mfma_f32_16x16x32_bf16(A1, Bb, ac1, 0, 0, 0);
    }
    float vb = a.attn_b[n0 + fr];
#pragma unroll
    for (int j = 0; j < 4; ++j) {
      a.qW[(size_t)(rb0 + g * 4 + j) * 512 + n0 + fr]      = ac0[j] + vb;
      a.qW[(size_t)(rb0 + 16 + g * 4 + j) * 512 + n0 + fr] = ac1[j] + vb;
    }
  } else if (blk < 255) {
    const int NT = 239 * 512;
    const int ARENA_Q = 1507328;
    const int T_TOTAL = ARENA_Q + 1024 + 3 * 16384;
    int tid = (blk - 16) * 512 + t;
    for (int i = tid; i < T_TOTAL; i += NT) {
      if (i < ARENA_Q) {
        int e = i * 4;
        float4 v = {0.f, 0.f, 0.f, 0.f};
        if (e < 262144) {                      // Wenc = attn_W[:, 512:]
          int o = e >> 9, k = e & 511;
          v = *(const float4*)(a.attn_W + (size_t)o * 1024 + 512 + k);
        } else if (e < 786432) {               // Wcat
          int e2 = e - 262144; int o = e2 >> 10, k = e2 & 1023;
          v = *(const float4*)(a.cat_W + (size_t)o * 1024 + k);
        } else if (e < 3932160) {              // Wg0p [2048=4o+g][1536]
          int e2 = e - 786432; int row = e2 / 1536, k = e2 % 1536;
          int o = row >> 2, gt = row & 3;
          if (gt == 0)      v = (k < 1024) ? *(const float4*)(a.W_ih0 + (size_t)o * 1024 + k)
                                           : *(const float4*)(a.W_hh0 + (size_t)o * 512 + k - 1024);
          else if (gt == 1) v = (k < 1024) ? *(const float4*)(a.W_ih0 + (size_t)(512 + o) * 1024 + k)
                                           : *(const float4*)(a.W_hh0 + (size_t)(512 + o) * 512 + k - 1024);
          else if (gt == 2) { if (k < 1024)  v = *(const float4*)(a.W_ih0 + (size_t)(1024 + o) * 1024 + k); }
          else              { if (k >= 1024) v = *(const float4*)(a.W_hh0 + (size_t)(1024 + o) * 512 + k - 1024); }
        } else {                               // Wg1p [2048=4o+g][1024]
          int e2 = e - 3932160; int row = e2 >> 10, k = e2 & 1023;
          int o = row >> 2, gt = row & 3;
          if (gt == 0)      v = (k < 512) ? *(const float4*)(a.W_ih1 + (size_t)o * 512 + k)
                                          : *(const float4*)(a.W_hh1 + (size_t)o * 512 + k - 512);
          else if (gt == 1) v = (k < 512) ? *(const float4*)(a.W_ih1 + (size_t)(512 + o) * 512 + k)
                                          : *(const float4*)(a.W_hh1 + (size_t)(512 + o) * 512 + k - 512);
          else if (gt == 2) { if (k < 512)  v = *(const float4*)(a.W_ih1 + (size_t)(1024 + o) * 512 + k); }
          else              { if (k >= 512) v = *(const float4*)(a.W_hh1 + (size_t)(1024 + o) * 512 + k - 512); }
        }
        ushort4 u;
        u.x = f2bf(v.x); u.y = f2bf(v.y); u.z = f2bf(v.z); u.w = f2bf(v.w);
        *(ushort4*)(a.arena + e) = u;
      } else {
        int i2 = i - ARENA_Q;
        if (i2 < 1024) {                       // biases, 4o+g quads
          int r4 = i2 * 4; int layer = r4 >> 11; int r = r4 & 2047; int o = r >> 2;
          const float* bi = layer ? a.b_ih1 : a.b_ih0;
          const float* bh = layer ? a.b_hh1 : a.b_hh0;
          float4 v;
          v.x = bi[o] + bh[o];
          v.y = bi[512 + o] + bh[512 + o];
          v.z = bi[1024 + o];
          v.w = bh[1024 + o];
          *(float4*)((layer ? a.biasg1 : a.biasg0) + r) = v;
        } else if (i2 < 1024 + 16384) {        // emb gather
          int j = (i2 - 1024) * 4; int b = j >> 9, i0 = j & 511;
          float4 v = *(const float4*)(a.wdv + (size_t)b * (Vdim * Hdim) + (size_t)a.ids[b] * 512 + i0);
          ushort4 u;
          u.x = f2bf(v.x); u.y = f2bf(v.y); u.z = f2bf(v.z); u.w = f2bf(v.w);
          *(ushort4*)(a.X0bf + b * 1536 + i0) = u;
        } else if (i2 < 1024 + 32768) {        // lh0 -> X0bf[:,1024:]
          int j = (i2 - 1024 - 16384) * 4; int b = j >> 9, i0 = j & 511;
          float4 v = *(const float4*)(a.lh + (size_t)b * 512 + i0);
          ushort4 u;
          u.x = f2bf(v.x); u.y = f2bf(v.y); u.z = f2bf(v.z); u.w = f2bf(v.w);
          *(ushort4*)(a.X0bf + b * 1536 + 1024 + i0) = u;
        } else {                               // q -> X1bf[:,512:]
          int j = (i2 - 1024 - 32768) * 4; int b = j >> 9, i0 = j & 511;
          float4 v = *(const float4*)(a.lh + 65536 + (size_t)b * 512 + i0);
          ushort4 u;
          u.x = f2bf(v.x); u.y = f2bf(v.y); u.z = f2bf(v.z); u.w = f2bf(v.w);
          *(ushort4*)(a.X1bf + b * 1024 + 512 + i0) = u;
        }
      }
    }
  } else {                                     // blk 255: mask dtype detect
    int* sfp = (int*)smem;
    if (t == 0) *sfp = 0;
    __syncthreads();
    const uint32_t* m32 = (const uint32_t*)a.mask;
    int found = 0;
    for (int i = t; i < 16384; i += 512)
      if (m32[i] & 0xffffff00u) found = 1;     // nonzero byte at pos%4!=0 => byte mask
    if (found) *sfp = 1;
    __syncthreads();
    if (t == 0) *a.flag = *sfp;
  }
  gridg.sync();

  // ================= S2: attention energies -> scores =================
  // Each block: l-pair {2*blk, 2*blk+1}, each l in two o-halves (oh pairs
  // back-to-back so the A-tile is cache-hot on the second half).
  // Per (l,oh): tile 128(b) x 256(o); wave computes 128x32 -> acc[8][2]=64 VGPR.
  {
    u16* As = (u16*)smem;                      // [2][128][40]
    u16* Bs = (u16*)(smem + 20480);            // [2][256][40]
    float* part = (float*)(smem + 61440);      // [8][128]
    float* sacc = (float*)(smem + 65536);      // [128]
    const u16* Wenc = a.arena;
    const int arow = t >> 2;                   // 0..127
    const int aks = (t & 3) * 8;

    for (int it = 0; it < 4; ++it) {
      int l  = blk * 2 + (it >> 1);
      int oh = it & 1;
      int ob = oh * 256;
      f32x4 acc[8][2];
#pragma unroll
      for (int i = 0; i < 8; ++i) {
        acc[i][0] = (f32x4){0.f, 0.f, 0.f, 0.f};
        acc[i][1] = (f32x4){0.f, 0.f, 0.f, 0.f};
      }
      const float* abase = a.enc + ((size_t)l * 128 + arow) * 512 + aks;
      const u16* bbase0 = Wenc + (size_t)(ob + arow) * 512 + aks;
      const u16* bbase1 = bbase0 + (size_t)128 * 512;

      float4 ra0 = *(const float4*)abase;
      float4 ra1 = *(const float4*)(abase + 4);
      uint4 rb0 = *(const uint4*)bbase0;
      uint4 rb1 = *(const uint4*)bbase1;

#pragma unroll 2
      for (int step = 0; step < 16; ++step) {
        int sel = step & 1;
        __syncthreads();
        uint4 ap;
        ap.x = pk2(ra0.x, ra0.y); ap.y = pk2(ra0.z, ra0.w);
        ap.z = pk2(ra1.x, ra1.y); ap.w = pk2(ra1.z, ra1.w);
        *(uint4*)(As + sel * 5120 + arow * 40 + aks) = ap;
        *(uint4*)(Bs + sel * 10240 + arow * 40 + aks) = rb0;
        *(uint4*)(Bs + sel * 10240 + (128 + arow) * 40 + aks) = rb1;
        if (step < 15) {
          int kt = (step + 1) * 32;
          ra0 = *(const float4*)(abase + kt);
          ra1 = *(const float4*)(abase + kt + 4);
          rb0 = *(const uint4*)(bbase0 + kt);
          rb1 = *(const uint4*)(bbase1 + kt);
        }
        __syncthreads();
        bf16x8 b0 = *(const bf16x8*)(Bs + sel * 10240 + (wid * 32 + fr) * 40 + kof);
        bf16x8 b1 = *(const bf16x8*)(Bs + sel * 10240 + (wid * 32 + 16 + fr) * 40 + kof);
#pragma unroll
        for (int mi = 0; mi < 8; ++mi) {
          bf16x8 av = *(const bf16x8*)(As + sel * 5120 + (mi * 16 + fr) * 40 + kof);
          acc[mi][0] = __builtin_amdgcn_mfma_f32_16x16x32_bf16(av, b0, acc[mi][0], 0, 0, 0);
          acc[mi][1] = __builtin_amdgcn_mfma_f32_16x16x32_bf16(av, b1, acc[mi][1], 0, 0, 0);
        }
      }
      // epilogue: +qW, tanh, *scW, reduce over this oh's 32 cols per wave
#pragma unroll
      for (int mi = 0; mi < 8; ++mi) {
        float rs0 = 0.f, rs1 = 0.f, rs2 = 0.f, rs3 = 0.f;
#pragma unroll
        for (int ni = 0; ni < 2; ++ni) {
          int o = ob + wid * 32 + ni * 16 + fr;
          float sw = a.scW[o];
          int brow = mi * 16 + g * 4;
          rs0 += sw * fast_tanh(acc[mi][ni][0] + a.qW[(size_t)(brow + 0) * 512 + o]);
          rs1 += sw * fast_tanh(acc[mi][ni][1] + a.qW[(size_t)(brow + 1) * 512 + o]);
          rs2 += sw * fast_tanh(acc[mi][ni][2] + a.qW[(size_t)(brow + 2) * 512 + o]);
          rs3 += sw * fast_tanh(acc[mi][ni][3] + a.qW[(size_t)(brow + 3) * 512 + o]);
        }
#pragma unroll
        for (int d = 1; d < 16; d <<= 1) {
          rs0 += __shfl_xor(rs0, d);
          rs1 += __shfl_xor(rs1, d);
          rs2 += __shfl_xor(rs2, d);
          rs3 += __shfl_xor(rs3, d);
        }
        if (fr < 4) {
          float v = (fr == 0) ? rs0 : (fr == 1) ? rs1 : (fr == 2) ? rs2 : rs3;
          part[wid * 128 + mi * 16 + g * 4 + fr] = v;
        }
      }
      __syncthreads();
      if (t < 128) {
        float s = 0.f;
#pragma unroll
        for (int w2 = 0; w2 < 8; ++w2) s += part[w2 * 128 + t];
        if (oh == 0) sacc[t] = s;
        else a.scores[(size_t)t * 512 + l] = sacc[t] + s;
      }
    }
  }
  gridg.sync();

  // ================= S3: mask + softmax + context =================
  {
    float* wgt  = (float*)smem;                // 512
    float* redm = wgt + 512;                   // 8
    float* reds = redm + 8;                    // 8
    float* ps   = (float*)(smem + 4096);       // [4][128][2]
    int b = blk >> 1, ch = blk & 1;
    float s = a.scores[(size_t)b * 512 + t];
    bool isbyte = (*a.flag != 0);
    bool m = isbyte ? (((const uint8_t*)a.mask)[b * 512 + t] != 0)
                    : (((const int*)a.mask)[b * 512 + t] != 0);
    float v = m ? -1e12f : s;
    float mx = v;
#pragma unroll
    for (int d = 1; d < 64; d <<= 1) mx = fmaxf(mx, __shfl_xor(mx, d));
    if (lane == 0) redm[wid] = mx;
    __syncthreads();
    mx = redm[0];
#pragma unroll
    for (int w2 = 1; w2 < 8; ++w2) mx = fmaxf(mx, redm[w2]);
    float e = __expf(v - mx);
    float sm = e;
#pragma unroll
    for (int d = 1; d < 64; d <<= 1) sm += __shfl_xor(sm, d);
    if (lane == 0) reds[wid] = sm;
    __syncthreads();
    sm = reds[0] + reds[1] + reds[2] + reds[3] + reds[4] + reds[5] + reds[6] + reds[7];
    wgt[t] = e / sm;
    __syncthreads();
    int cp = t & 127, lq = t >> 7;
    int col = ch * 256 + cp * 2;
    float a0 = 0.f, a1 = 0.f;
    for (int l = lq * 128; l < lq * 128 + 128; ++l) {
      float wl = wgt[l];
      if (wl != 0.0f) {
        float2 ev = *(const float2*)(a.enc + ((size_t)l * 128 + b) * 512 + col);
        a0 += wl * ev.x;
        a1 += wl * ev.y;
      }
    }
    ps[(lq * 128 + cp) * 2 + 0] = a0;
    ps[(lq * 128 + cp) * 2 + 1] = a1;
    __syncthreads();
    if (t < 128) {
      float r0 = ps[t * 2] + ps[(128 + t) * 2] + ps[(256 + t) * 2] + ps[(384 + t) * 2];
      float r1 = ps[t * 2 + 1] + ps[(128 + t) * 2 + 1] + ps[(256 + t) * 2 + 1] + ps[(384 + t) * 2 + 1];
      uint32_t packed = pk2(r0, r1);
      int cc = ch * 256 + t * 2;
      *(uint32_t*)(a.X0bf + b * 1536 + 512 + cc) = packed;
      *(uint32_t*)(a.c1bf + b * 1024 + 512 + cc) = packed;
    }
  }
  gridg.sync();

  // ================= S4: GRU layer 0 =================
  if (blk < 128)
    gru_stage(a, a.X0bf, 1536, a.arena + 786432, a.biasg0, a.lh, a.h0o, a.X1bf,
              1536, blk, t, (float*)smem);
  gridg.sync();

  // ================= S5: GRU layer 1 =================
  if (blk < 128)
    gru_stage(a, a.X1bf, 1024, a.arena + 3932160, a.biasg1, a.lh + 65536, a.h1o, a.c1bf,
              1024, blk, t, (float*)smem);
  gridg.sync();

  // ================= S6: output = tanh(c1 @ Wcat^T + cat_b) =================
  if (blk < 32) {
    int wv = wid;
    int n0 = blk * 16;
    f32x4 acc = {0.f, 0.f, 0.f, 0.f};
    const u16* Xr = a.c1bf + (size_t)(wv * 16 + fr) * 1024;
    const u16* Wr = a.arena + 262144 + (size_t)(n0 + fr) * 1024;
#pragma unroll 4
    for (int kt = 0; kt < 1024; kt += 32) {
      bf16x8 av = *(const bf16x8*)(Xr + kt + kof);
      bf16x8 bv = *(const bf16x8*)(Wr + kt + kof);
      acc = __builtin_amdgcn_mfma_f32_16x16x32_bf16(av, bv, acc, 0, 0, 0);
    }
    float vb = a.cat_b[n0 + fr];
#pragma unroll
    for (int j = 0; j < 4; ++j)
      a.out[(size_t)(wv * 16 + g * 4 + j) * 512 + n0 + fr] = tanhf(acc[j] + vb);
  }
}

extern "C" void kernel_launch(void* const* d_in, const int* in_sizes, int n_in,
                              void* d_out, int out_size, void* d_ws, size_t ws_size,
                              hipStream_t stream) {
  float* out = (float*)d_out;

  float* ws     = (float*)d_ws;
  float* qW     = ws;                        // 65536
  float* scores = ws + 65536;                // 65536
  float* biasg0 = ws + 131072;               // 2048
  float* biasg1 = ws + 133120;               // 2048
  int*   flag   = (int*)(ws + 135168);       // 16
  u16*   arena  = (u16*)(ws + 135184);       // 6029312 u16 = 3014656 f
  u16*   X0bf   = (u16*)(ws + 3149840);      // 196608 u16
  u16*   X1bf   = (u16*)(ws + 3248144);      // 131072 u16
  u16*   c1bf   = (u16*)(ws + 3313680);      // 131072 u16

  KArgs ka;
  ka.ids    = (const int*)  d_in[0];
  ka.lh     = (const float*)d_in[1];
  ka.wdv    = (const float*)d_in[2];
  ka.enc    = (const float*)d_in[3];
  ka.mask   = d_in[4];
  ka.attn_W = (const float*)d_in[5];
  ka.attn_b = (const float*)d_in[6];
  ka.scW    = (const float*)d_in[7];
  ka.cat_W  = (const float*)d_in[8];
  ka.cat_b  = (const float*)d_in[9];
  ka.W_ih0  = (const float*)d_in[10];
  ka.W_hh0  = (const float*)d_in[11];
  ka.b_ih0  = (const float*)d_in[12];
  ka.b_hh0  = (const float*)d_in[13];
  ka.W_ih1  = (const float*)d_in[14];
  ka.W_hh1  = (const float*)d_in[15];
  ka.b_ih1  = (const float*)d_in[16];
  ka.b_hh1  = (const float*)d_in[17];
  ka.out = out; ka.h0o = out + 65536; ka.h1o = out + 131072;
  ka.qW = qW; ka.scores = scores; ka.biasg0 = biasg0; ka.biasg1 = biasg1;
  ka.flag = flag; ka.arena = arena; ka.X0bf = X0bf; ka.X1bf = X1bf; ka.c1bf = c1bf;

  void* params[] = { (void*)&ka };
  hipLaunchCooperativeKernel((const void*)mega_kernel, dim3(256), dim3(512),
                             params, SMEM_BYTES, stream);
}

// Round 8
// 187.774 us; speedup vs baseline: 3.5800x; 1.9617x over previous
//
#include <hip/hip_runtime.h>
#include <stdint.h>

#define Hdim 512
#define Bdim 128
#define Ldim 512
#define Vdim 2048

typedef unsigned short u16;
using f32x4  = float  __attribute__((ext_vector_type(4)));
using bf16x8 = __bf16 __attribute__((ext_vector_type(8)));

__device__ inline u16 f2bf(float x) {
  uint32_t u = __float_as_uint(x);
  u += 0x7fffu + ((u >> 16) & 1u);   // RNE
  return (u16)(u >> 16);
}
__device__ inline uint32_t pk2(float lo, float hi) {
  return (uint32_t)f2bf(lo) | ((uint32_t)f2bf(hi) << 16);
}
__device__ inline float fast_tanh(float x) {
  return 1.0f - 2.0f / (__expf(2.0f * x) + 1.0f);
}
__device__ inline float fast_sig(float x) { return 1.0f / (1.0f + __expf(-x)); }

__device__ inline bf16x8 pack_bf8(float4 x, float4 y) {
  union { uint32_t d[4]; bf16x8 v; } r;
  r.d[0] = pk2(x.x, x.y); r.d[1] = pk2(x.z, x.w);
  r.d[2] = pk2(y.x, y.y); r.d[3] = pk2(y.z, y.w);
  return r.v;
}

// =======================================================================
// prep: blk<16 -> qW GEMM (f32 direct, in-reg cvt); blk==16 -> mask detect;
// blk>=17 -> bf16 weight arena + fused biases + emb gather + lh copies.
// arena: Wenc@0 (512x512), Wcat@262144 (512x1024), Wg0p@786432 (2048x1536),
//        Wg1p@3932160 (2048x1024)  total 6029312 u16
// =======================================================================
__global__ __launch_bounds__(512)
void prep_kernel(const float* __restrict__ lh, const float* __restrict__ attn_W,
                 const float* __restrict__ attn_b, const float* __restrict__ cat_W,
                 const float* __restrict__ W_ih0, const float* __restrict__ W_hh0,
                 const float* __restrict__ W_ih1, const float* __restrict__ W_hh1,
                 const float* __restrict__ b_ih0, const float* __restrict__ b_hh0,
                 const float* __restrict__ b_ih1, const float* __restrict__ b_hh1,
                 const float* __restrict__ wdv, const int* __restrict__ ids,
                 const void* __restrict__ mask,
                 float* __restrict__ qW, u16* __restrict__ arena,
                 float* __restrict__ biasg0, float* __restrict__ biasg1,
                 u16* __restrict__ X0bf, u16* __restrict__ X1bf, int* __restrict__ flag) {
  int blk = blockIdx.x, t = threadIdx.x;
  int lane = t & 63, wid = t >> 6;
  int fr = lane & 15, g = lane >> 4, kof = g * 8;

  if (blk < 16) {
    // qW = q @ attn_W[:, :512]^T + attn_b
    int mh = wid & 3, nh = wid >> 2;
    int n0 = blk * 32 + nh * 16;
    int rb0 = mh * 32;
    f32x4 ac0 = {0.f, 0.f, 0.f, 0.f}, ac1 = {0.f, 0.f, 0.f, 0.f};
    const float* q = lh + 65536;
#pragma unroll 2
    for (int kt = 0; kt < 512; kt += 32) {
      const float* qr0 = q + (size_t)(rb0 + fr) * 512 + kt + kof;
      const float* qr1 = qr0 + 16 * 512;
      const float* wr  = attn_W + (size_t)(n0 + fr) * 1024 + kt + kof;
      float4 x0 = *(const float4*)qr0, x1 = *(const float4*)(qr0 + 4);
      float4 y0 = *(const float4*)qr1, y1 = *(const float4*)(qr1 + 4);
      float4 w0 = *(const float4*)wr,  w1 = *(const float4*)(wr + 4);
      bf16x8 A0 = pack_bf8(x0, x1), A1 = pack_bf8(y0, y1), Bb = pack_bf8(w0, w1);
      ac0 = __builtin_amdgcn_mfma_f32_16x16x32_bf16(A0, Bb, ac0, 0, 0, 0);
      ac1 = __builtin_amdgcn_mfma_f32_16x16x32_bf16(A1, Bb, ac1, 0, 0, 0);
    }
    float vb = attn_b[n0 + fr];
#pragma unroll
    for (int j = 0; j < 4; ++j) {
      qW[(size_t)(rb0 + g * 4 + j) * 512 + n0 + fr]      = ac0[j] + vb;
      qW[(size_t)(rb0 + 16 + g * 4 + j) * 512 + n0 + fr] = ac1[j] + vb;
    }
    return;
  }
  if (blk == 16) {                              // mask dtype detect
    __shared__ int sf;
    if (t == 0) sf = 0;
    __syncthreads();
    const uint32_t* m32 = (const uint32_t*)mask;
    int found = 0;
    for (int i = t; i < 16384; i += 512)
      if (m32[i] & 0xffffff00u) found = 1;      // nonzero byte at pos%4!=0 => byte mask
    if (found) sf = 1;
    __syncthreads();
    if (t == 0) *flag = sf;
    return;
  }
  // arena + biases + gather, one quad per thread
  const int ARENA_Q = 1507328;
  int i = (blk - 17) * 512 + t;
  if (i < ARENA_Q) {
    int e = i * 4;
    float4 v = {0.f, 0.f, 0.f, 0.f};
    if (e < 262144) {                           // Wenc = attn_W[:, 512:]
      int o = e >> 9, k = e & 511;
      v = *(const float4*)(attn_W + (size_t)o * 1024 + 512 + k);
    } else if (e < 786432) {                    // Wcat
      int e2 = e - 262144; int o = e2 >> 10, k = e2 & 1023;
      v = *(const float4*)(cat_W + (size_t)o * 1024 + k);
    } else if (e < 3932160) {                   // Wg0p [2048=4o+g][1536]
      int e2 = e - 786432; int row = e2 / 1536, k = e2 % 1536;
      int o = row >> 2, gt = row & 3;
      if (gt == 0)      v = (k < 1024) ? *(const float4*)(W_ih0 + (size_t)o * 1024 + k)
                                       : *(const float4*)(W_hh0 + (size_t)o * 512 + k - 1024);
      else if (gt == 1) v = (k < 1024) ? *(const float4*)(W_ih0 + (size_t)(512 + o) * 1024 + k)
                                       : *(const float4*)(W_hh0 + (size_t)(512 + o) * 512 + k - 1024);
      else if (gt == 2) { if (k < 1024)  v = *(const float4*)(W_ih0 + (size_t)(1024 + o) * 1024 + k); }
      else              { if (k >= 1024) v = *(const float4*)(W_hh0 + (size_t)(1024 + o) * 512 + k - 1024); }
    } else {                                    // Wg1p [2048=4o+g][1024]
      int e2 = e - 3932160; int row = e2 >> 10, k = e2 & 1023;
      int o = row >> 2, gt = row & 3;
      if (gt == 0)      v = (k < 512) ? *(const float4*)(W_ih1 + (size_t)o * 512 + k)
                                      : *(const float4*)(W_hh1 + (size_t)o * 512 + k - 512);
      else if (gt == 1) v = (k < 512) ? *(const float4*)(W_ih1 + (size_t)(512 + o) * 512 + k)
                                      : *(const float4*)(W_hh1 + (size_t)(512 + o) * 512 + k - 512);
      else if (gt == 2) { if (k < 512)  v = *(const float4*)(W_ih1 + (size_t)(1024 + o) * 512 + k); }
      else              { if (k >= 512) v = *(const float4*)(W_hh1 + (size_t)(1024 + o) * 512 + k - 512); }
    }
    ushort4 u;
    u.x = f2bf(v.x); u.y = f2bf(v.y); u.z = f2bf(v.z); u.w = f2bf(v.w);
    *(ushort4*)(arena + e) = u;
    return;
  }
  int i2 = i - ARENA_Q;
  if (i2 < 1024) {                              // biases, 4o+g quads
    int r4 = i2 * 4; int layer = r4 >> 11; int r = r4 & 2047; int o = r >> 2;
    const float* bi = layer ? b_ih1 : b_ih0;
    const float* bh = layer ? b_hh1 : b_hh0;
    float4 v;
    v.x = bi[o] + bh[o];
    v.y = bi[512 + o] + bh[512 + o];
    v.z = bi[1024 + o];
    v.w = bh[1024 + o];
    *(float4*)((layer ? biasg1 : biasg0) + r) = v;
  } else if (i2 < 1024 + 16384) {               // emb gather
    int j = (i2 - 1024) * 4; int b = j >> 9, i0 = j & 511;
    float4 v = *(const float4*)(wdv + (size_t)b * (Vdim * Hdim) + (size_t)ids[b] * 512 + i0);
    ushort4 u;
    u.x = f2bf(v.x); u.y = f2bf(v.y); u.z = f2bf(v.z); u.w = f2bf(v.w);
    *(ushort4*)(X0bf + b * 1536 + i0) = u;
  } else if (i2 < 1024 + 32768) {               // lh0 -> X0bf[:,1024:]
    int j = (i2 - 1024 - 16384) * 4; int b = j >> 9, i0 = j & 511;
    float4 v = *(const float4*)(lh + (size_t)b * 512 + i0);
    ushort4 u;
    u.x = f2bf(v.x); u.y = f2bf(v.y); u.z = f2bf(v.z); u.w = f2bf(v.w);
    *(ushort4*)(X0bf + b * 1536 + 1024 + i0) = u;
  } else if (i2 < 1024 + 49152) {               // q -> X1bf[:,512:]
    int j = (i2 - 1024 - 32768) * 4; int b = j >> 9, i0 = j & 511;
    float4 v = *(const float4*)(lh + 65536 + (size_t)b * 512 + i0);
    ushort4 u;
    u.x = f2bf(v.x); u.y = f2bf(v.y); u.z = f2bf(v.z); u.w = f2bf(v.w);
    *(ushort4*)(X1bf + b * 1024 + 512 + i0) = u;
  }
}

// =======================================================================
// attention energies. grid 1024: one (l, oh) 128x256 tile per block.
// l = (blk>>4)*8 + (blk&7); oh = (blk>>3)&1  -> both oh of an l on same XCD.
// A = enc f32 (reg-staged + cvt), B = Wenc bf16 (reg-staged), dbuf LDS,
// rows padded to 40 u16. acc[8][2] = 64 VGPR (no spill; R7-verified body).
// =======================================================================
__global__ __launch_bounds__(512)
void attn_kernel(const float* __restrict__ enc, const u16* __restrict__ Wenc,
                 const float* __restrict__ qW, const float* __restrict__ scW,
                 float* __restrict__ scores_p) {
  __shared__ __align__(16) u16 As[2][128 * 40];
  __shared__ __align__(16) u16 Bs[2][256 * 40];
  __shared__ float part[8 * 128];
  int blk = blockIdx.x, t = threadIdx.x;
  int lane = t & 63, wid = t >> 6;
  int fr = lane & 15, g = lane >> 4, kof = g * 8;
  int l  = (blk >> 4) * 8 + (blk & 7);
  int oh = (blk >> 3) & 1;
  int ob = oh * 256;
  const int arow = t >> 2;             // 0..127
  const int aks = (t & 3) * 8;

  f32x4 acc[8][2];
#pragma unroll
  for (int i = 0; i < 8; ++i) {
    acc[i][0] = (f32x4){0.f, 0.f, 0.f, 0.f};
    acc[i][1] = (f32x4){0.f, 0.f, 0.f, 0.f};
  }
  const float* abase = enc + ((size_t)l * 128 + arow) * 512 + aks;
  const u16* bbase0 = Wenc + (size_t)(ob + arow) * 512 + aks;
  const u16* bbase1 = bbase0 + (size_t)128 * 512;

  float4 ra0 = *(const float4*)abase;
  float4 ra1 = *(const float4*)(abase + 4);
  uint4 rb0 = *(const uint4*)bbase0;
  uint4 rb1 = *(const uint4*)bbase1;

#pragma unroll 2
  for (int step = 0; step < 16; ++step) {
    int sel = step & 1;
    __syncthreads();
    uint4 ap;
    ap.x = pk2(ra0.x, ra0.y); ap.y = pk2(ra0.z, ra0.w);
    ap.z = pk2(ra1.x, ra1.y); ap.w = pk2(ra1.z, ra1.w);
    *(uint4*)(&As[sel][arow * 40 + aks]) = ap;
    *(uint4*)(&Bs[sel][arow * 40 + aks]) = rb0;
    *(uint4*)(&Bs[sel][(128 + arow) * 40 + aks]) = rb1;
    if (step < 15) {
      int kt = (step + 1) * 32;
      ra0 = *(const float4*)(abase + kt);
      ra1 = *(const float4*)(abase + kt + 4);
      rb0 = *(const uint4*)(bbase0 + kt);
      rb1 = *(const uint4*)(bbase1 + kt);
    }
    __syncthreads();
    bf16x8 b0 = *(const bf16x8*)(&Bs[sel][(wid * 32 + fr) * 40 + kof]);
    bf16x8 b1 = *(const bf16x8*)(&Bs[sel][(wid * 32 + 16 + fr) * 40 + kof]);
#pragma unroll
    for (int mi = 0; mi < 8; ++mi) {
      bf16x8 av = *(const bf16x8*)(&As[sel][(mi * 16 + fr) * 40 + kof]);
      acc[mi][0] = __builtin_amdgcn_mfma_f32_16x16x32_bf16(av, b0, acc[mi][0], 0, 0, 0);
      acc[mi][1] = __builtin_amdgcn_mfma_f32_16x16x32_bf16(av, b1, acc[mi][1], 0, 0, 0);
    }
  }
  // epilogue: +qW, tanh, *scW, reduce over this block's 256 o's
#pragma unroll
  for (int mi = 0; mi < 8; ++mi) {
    float rs0 = 0.f, rs1 = 0.f, rs2 = 0.f, rs3 = 0.f;
#pragma unroll
    for (int ni = 0; ni < 2; ++ni) {
      int o = ob + wid * 32 + ni * 16 + fr;
      float sw = scW[o];
      int brow = mi * 16 + g * 4;
      rs0 += sw * fast_tanh(acc[mi][ni][0] + qW[(size_t)(brow + 0) * 512 + o]);
      rs1 += sw * fast_tanh(acc[mi][ni][1] + qW[(size_t)(brow + 1) * 512 + o]);
      rs2 += sw * fast_tanh(acc[mi][ni][2] + qW[(size_t)(brow + 2) * 512 + o]);
      rs3 += sw * fast_tanh(acc[mi][ni][3] + qW[(size_t)(brow + 3) * 512 + o]);
    }
#pragma unroll
    for (int d = 1; d < 16; d <<= 1) {
      rs0 += __shfl_xor(rs0, d);
      rs1 += __shfl_xor(rs1, d);
      rs2 += __shfl_xor(rs2, d);
      rs3 += __shfl_xor(rs3, d);
    }
    if (fr < 4) {
      float v = (fr == 0) ? rs0 : (fr == 1) ? rs1 : (fr == 2) ? rs2 : rs3;
      part[wid * 128 + mi * 16 + g * 4 + fr] = v;
    }
  }
  __syncthreads();
  if (t < 128) {
    float s = 0.f;
#pragma unroll
    for (int w2 = 0; w2 < 8; ++w2) s += part[w2 * 128 + t];
    scores_p[(size_t)(oh * 128 + t) * 512 + l] = s;
  }
}

// =======================================================================
// mask + softmax + context (f32 enc). grid 512 = (b, col-chunk of 128).
// =======================================================================
__global__ __launch_bounds__(256)
void softctx_kernel(const float* __restrict__ sp, const void* __restrict__ maskp,
                    const int* __restrict__ flag, const float* __restrict__ enc,
                    u16* __restrict__ X0bf, u16* __restrict__ c1bf) {
  int bx = blockIdx.x;
  int b = bx >> 2, c = bx & 3;
  int t = threadIdx.x;
  __shared__ float wgt[512];
  __shared__ float redm[4], reds[4];
  __shared__ float ps[4][64][2];
  int l0 = t, l1 = t + 256;
  float s0 = sp[(size_t)b * 512 + l0] + sp[(size_t)(128 + b) * 512 + l0];
  float s1 = sp[(size_t)b * 512 + l1] + sp[(size_t)(128 + b) * 512 + l1];
  bool isbyte = (*flag != 0);
  bool m0, m1;
  if (isbyte) {
    m0 = ((const uint8_t*)maskp)[b * 512 + l0] != 0;
    m1 = ((const uint8_t*)maskp)[b * 512 + l1] != 0;
  } else {
    m0 = ((const int*)maskp)[b * 512 + l0] != 0;
    m1 = ((const int*)maskp)[b * 512 + l1] != 0;
  }
  float v0 = m0 ? -1e12f : s0;
  float v1 = m1 ? -1e12f : s1;
  float mx = fmaxf(v0, v1);
#pragma unroll
  for (int d = 1; d < 64; d <<= 1) mx = fmaxf(mx, __shfl_xor(mx, d));
  if ((t & 63) == 0) redm[t >> 6] = mx;
  __syncthreads();
  mx = fmaxf(fmaxf(redm[0], redm[1]), fmaxf(redm[2], redm[3]));
  float e0 = __expf(v0 - mx), e1 = __expf(v1 - mx);
  float sm = e0 + e1;
#pragma unroll
  for (int d = 1; d < 64; d <<= 1) sm += __shfl_xor(sm, d);
  if ((t & 63) == 0) reds[t >> 6] = sm;
  __syncthreads();
  sm = reds[0] + reds[1] + reds[2] + reds[3];
  float inv = 1.0f / sm;
  wgt[l0] = e0 * inv;
  wgt[l1] = e1 * inv;
  __syncthreads();
  int cp = t & 63, lq = t >> 6;
  int col = c * 128 + cp * 2;
  float a0 = 0.f, a1 = 0.f;
  for (int l = lq * 128; l < lq * 128 + 128; ++l) {
    float wl = wgt[l];
    if (wl != 0.0f) {
      float2 ev = *(const float2*)(enc + ((size_t)l * 128 + b) * 512 + col);
      a0 += wl * ev.x;
      a1 += wl * ev.y;
    }
  }
  ps[lq][cp][0] = a0;
  ps[lq][cp][1] = a1;
  __syncthreads();
  if (t < 64) {
    float r0 = ps[0][t][0] + ps[1][t][0] + ps[2][t][0] + ps[3][t][0];
    float r1 = ps[0][t][1] + ps[1][t][1] + ps[2][t][1] + ps[3][t][1];
    int cc = c * 128 + t * 2;
    uint32_t packed = pk2(r0, r1);
    *(uint32_t*)(X0bf + b * 1536 + 512 + cc) = packed;
    *(uint32_t*)(c1bf + b * 1024 + 512 + cc) = packed;
  }
}

// =======================================================================
// GRU layer: GEMM (gate-interleaved W: row 4o+g) + fused combine epilogue.
// grid 64 blocks (8 outputs each), block 256 (4 waves x 32 rows).
// =======================================================================
__global__ __launch_bounds__(256)
void gru_gemm_kernel(const u16* __restrict__ X, int ldx, const u16* __restrict__ Wp,
                     const float* __restrict__ biasp, const float* __restrict__ hprev,
                     int K, float* __restrict__ hout, u16* __restrict__ xdst) {
  __shared__ float ct[128][36];
  int n0 = blockIdx.x * 32;
  int t = threadIdx.x, lane = t & 63, w = t >> 6;
  int fr = lane & 15, g = lane >> 4, kof = g * 8;
  f32x4 acc[2][2];
#pragma unroll
  for (int i = 0; i < 2; ++i)
#pragma unroll
    for (int j = 0; j < 2; ++j) acc[i][j] = (f32x4){0.f, 0.f, 0.f, 0.f};
  const u16* Xr0 = X + (size_t)(w * 32 + fr) * ldx;
  const u16* Xr1 = Xr0 + (size_t)16 * ldx;
  const u16* Wr0 = Wp + (size_t)(n0 + fr) * K;
  const u16* Wr1 = Wp + (size_t)(n0 + 16 + fr) * K;
#pragma unroll 4
  for (int kt = 0; kt < K; kt += 32) {
    bf16x8 a0 = *(const bf16x8*)(Xr0 + kt + kof);
    bf16x8 a1 = *(const bf16x8*)(Xr1 + kt + kof);
    bf16x8 b0 = *(const bf16x8*)(Wr0 + kt + kof);
    bf16x8 b1 = *(const bf16x8*)(Wr1 + kt + kof);
    acc[0][0] = __builtin_amdgcn_mfma_f32_16x16x32_bf16(a0, b0, acc[0][0], 0, 0, 0);
    acc[0][1] = __builtin_amdgcn_mfma_f32_16x16x32_bf16(a0, b1, acc[0][1], 0, 0, 0);
    acc[1][0] = __builtin_amdgcn_mfma_f32_16x16x32_bf16(a1, b0, acc[1][0], 0, 0, 0);
    acc[1][1] = __builtin_amdgcn_mfma_f32_16x16x32_bf16(a1, b1, acc[1][1], 0, 0, 0);
  }
#pragma unroll
  for (int mi = 0; mi < 2; ++mi)
#pragma unroll
    for (int ni = 0; ni < 2; ++ni) {
      int col = ni * 16 + fr;
      float vb = biasp[n0 + col];
#pragma unroll
      for (int j = 0; j < 4; ++j)
        ct[w * 32 + 16 * mi + g * 4 + j][col] = acc[mi][ni][j] + vb;
    }
  __syncthreads();
#pragma unroll
  for (int i = 0; i < 4; ++i) {
    int u = t + i * 256;
    int b = u >> 3, ol = u & 7;
    float cr  = ct[b][ol * 4 + 0];
    float cz  = ct[b][ol * 4 + 1];
    float ci  = ct[b][ol * 4 + 2];
    float chh = ct[b][ol * 4 + 3];
    int o = blockIdx.x * 8 + ol;
    float r = fast_sig(cr), z = fast_sig(cz);
    float n = tanhf(ci + r * chh);
    float h = (1.0f - z) * n + z * hprev[b * 512 + o];
    hout[b * 512 + o] = h;
    xdst[b * 1024 + o] = f2bf(h);
  }
}

// =======================================================================
// thin GEMM, N-tile 32: C = act(X @ W^T + bias). grid N/32, block 256.
// =======================================================================
__global__ __launch_bounds__(256)
void thin_gemm32(const u16* __restrict__ X, int ldx, const u16* __restrict__ W,
                 const float* __restrict__ bias, float* __restrict__ C, int ldc,
                 int K, int act) {
  int n0 = blockIdx.x * 32;
  int t = threadIdx.x, lane = t & 63, w = t >> 6;
  int fr = lane & 15, g = lane >> 4, kof = g * 8;
  f32x4 acc[2][2];
#pragma unroll
  for (int i = 0; i < 2; ++i)
#pragma unroll
    for (int j = 0; j < 2; ++j) acc[i][j] = (f32x4){0.f, 0.f, 0.f, 0.f};
  const u16* Xr0 = X + (size_t)(w * 32 + fr) * ldx;
  const u16* Xr1 = Xr0 + (size_t)16 * ldx;
  const u16* Wr0 = W + (size_t)(n0 + fr) * K;
  const u16* Wr1 = W + (size_t)(n0 + 16 + fr) * K;
#pragma unroll 4
  for (int kt = 0; kt < K; kt += 32) {
    bf16x8 a0 = *(const bf16x8*)(Xr0 + kt + kof);
    bf16x8 a1 = *(const bf16x8*)(Xr1 + kt + kof);
    bf16x8 b0 = *(const bf16x8*)(Wr0 + kt + kof);
    bf16x8 b1 = *(const bf16x8*)(Wr1 + kt + kof);
    acc[0][0] = __builtin_amdgcn_mfma_f32_16x16x32_bf16(a0, b0, acc[0][0], 0, 0, 0);
    acc[0][1] = __builtin_amdgcn_mfma_f32_16x16x32_bf16(a0, b1, acc[0][1], 0, 0, 0);
    acc[1][0] = __builtin_amdgcn_mfma_f32_16x16x32_bf16(a1, b0, acc[1][0], 0, 0, 0);
    acc[1][1] = __builtin_amdgcn_mfma_f32_16x16x32_bf16(a1, b1, acc[1][1], 0, 0, 0);
  }
#pragma unroll
  for (int mi = 0; mi < 2; ++mi)
#pragma unroll
    for (int ni = 0; ni < 2; ++ni) {
      int col = n0 + ni * 16 + fr;
      float vb = bias[col];
#pragma unroll
      for (int j = 0; j < 4; ++j) {
        int row = w * 32 + 16 * mi + g * 4 + j;
        float v = acc[mi][ni][j] + vb;
        if (act) v = tanhf(v);
        C[(size_t)row * ldc + col] = v;
      }
    }
}

extern "C" void kernel_launch(void* const* d_in, const int* in_sizes, int n_in,
                              void* d_out, int out_size, void* d_ws, size_t ws_size,
                              hipStream_t stream) {
  const int*   ids    = (const int*)  d_in[0];
  const float* lh     = (const float*)d_in[1];
  const float* wdv    = (const float*)d_in[2];
  const float* enc    = (const float*)d_in[3];
  const void*  mask   = d_in[4];
  const float* attn_W = (const float*)d_in[5];
  const float* attn_b = (const float*)d_in[6];
  const float* scW    = (const float*)d_in[7];
  const float* cat_W  = (const float*)d_in[8];
  const float* cat_b  = (const float*)d_in[9];
  const float* W_ih0  = (const float*)d_in[10];
  const float* W_hh0  = (const float*)d_in[11];
  const float* b_ih0  = (const float*)d_in[12];
  const float* b_hh0  = (const float*)d_in[13];
  const float* W_ih1  = (const float*)d_in[14];
  const float* W_hh1  = (const float*)d_in[15];
  const float* b_ih1  = (const float*)d_in[16];
  const float* b_hh1  = (const float*)d_in[17];

  float* out = (float*)d_out;
  float* h0  = out + 65536;
  float* h1  = out + 131072;

  float* ws       = (float*)d_ws;
  float* qW       = ws;                      // 65536
  float* scores_p = ws + 65536;              // 131072 [2][128][512]
  float* biasg0   = ws + 196608;             // 2048
  float* biasg1   = ws + 198656;             // 2048
  int*   flag     = (int*)(ws + 200704);     // 16
  u16*   arena    = (u16*)(ws + 200720);     // 6029312 u16
  u16*   X0bf     = (u16*)(ws + 3215376);    // 196608 u16
  u16*   X1bf     = (u16*)(ws + 3313680);    // 131072 u16
  u16*   c1bf     = (u16*)(ws + 3379216);    // 131072 u16

  const u16* Wenc = arena;
  const u16* Wcat = arena + 262144;
  const u16* Wg0p = arena + 786432;
  const u16* Wg1p = arena + 3932160;

  prep_kernel<<<3059, 512, 0, stream>>>(lh, attn_W, attn_b, cat_W,
                                        W_ih0, W_hh0, W_ih1, W_hh1,
                                        b_ih0, b_hh0, b_ih1, b_hh1,
                                        wdv, ids, mask,
                                        qW, arena, biasg0, biasg1, X0bf, X1bf, flag);
  attn_kernel<<<1024, 512, 0, stream>>>(enc, Wenc, qW, scW, scores_p);
  softctx_kernel<<<512, 256, 0, stream>>>(scores_p, mask, flag, enc, X0bf, c1bf);
  gru_gemm_kernel<<<64, 256, 0, stream>>>(X0bf, 1536, Wg0p, biasg0, lh, 1536, h0, X1bf);
  gru_gemm_kernel<<<64, 256, 0, stream>>>(X1bf, 1024, Wg1p, biasg1, lh + 65536, 1024, h1, c1bf);
  thin_gemm32<<<16, 256, 0, stream>>>(c1bf, 1024, Wcat, cat_b, out, 512, 1024, 1);
}

// Round 10
// 172.953 us; speedup vs baseline: 3.8868x; 1.0857x over previous
//
#include <hip/hip_runtime.h>
#include <stdint.h>

#define Hdim 512
#define Bdim 128
#define Ldim 512
#define Vdim 2048

typedef unsigned short u16;
using f32x4  = float  __attribute__((ext_vector_type(4)));
using bf16x8 = __bf16 __attribute__((ext_vector_type(8)));

__device__ inline u16 f2bf(float x) {
  uint32_t u = __float_as_uint(x);
  u += 0x7fffu + ((u >> 16) & 1u);   // RNE
  return (u16)(u >> 16);
}
__device__ inline uint32_t pk2(float lo, float hi) {
  return (uint32_t)f2bf(lo) | ((uint32_t)f2bf(hi) << 16);
}
__device__ inline float fast_tanh(float x) {
  return 1.0f - 2.0f / (__expf(2.0f * x) + 1.0f);
}
__device__ inline float fast_sig(float x) { return 1.0f / (1.0f + __expf(-x)); }

__device__ inline bf16x8 pack_bf8(float4 x, float4 y) {
  union { uint32_t d[4]; bf16x8 v; } r;
  r.d[0] = pk2(x.x, x.y); r.d[1] = pk2(x.z, x.w);
  r.d[2] = pk2(y.x, y.y); r.d[3] = pk2(y.z, y.w);
  return r.v;
}

// =======================================================================
// prep: blk<16 -> qW GEMM (f32 direct, in-reg cvt); blk==16 -> mask detect;
// blk>=17 -> bf16 weight arena + fused biases + emb gather + lh copies.
// arena: Wenc@0 (512x512), Wcat@262144 (512x1024), Wg0p@786432 (2048x1536),
//        Wg1p@3932160 (2048x1024)  total 6029312 u16
// =======================================================================
__global__ __launch_bounds__(512)
void prep_kernel(const float* __restrict__ lh, const float* __restrict__ attn_W,
                 const float* __restrict__ attn_b, const float* __restrict__ cat_W,
                 const float* __restrict__ W_ih0, const float* __restrict__ W_hh0,
                 const float* __restrict__ W_ih1, const float* __restrict__ W_hh1,
                 const float* __restrict__ b_ih0, const float* __restrict__ b_hh0,
                 const float* __restrict__ b_ih1, const float* __restrict__ b_hh1,
                 const float* __restrict__ wdv, const int* __restrict__ ids,
                 const void* __restrict__ mask,
                 float* __restrict__ qW, u16* __restrict__ arena,
                 float* __restrict__ biasg0, float* __restrict__ biasg1,
                 u16* __restrict__ X0bf, u16* __restrict__ X1bf, int* __restrict__ flag) {
  int blk = blockIdx.x, t = threadIdx.x;
  int lane = t & 63, wid = t >> 6;
  int fr = lane & 15, g = lane >> 4, kof = g * 8;

  if (blk < 16) {
    // qW = q @ attn_W[:, :512]^T + attn_b
    int mh = wid & 3, nh = wid >> 2;
    int n0 = blk * 32 + nh * 16;
    int rb0 = mh * 32;
    f32x4 ac0 = {0.f, 0.f, 0.f, 0.f}, ac1 = {0.f, 0.f, 0.f, 0.f};
    const float* q = lh + 65536;
#pragma unroll 2
    for (int kt = 0; kt < 512; kt += 32) {
      const float* qr0 = q + (size_t)(rb0 + fr) * 512 + kt + kof;
      const float* qr1 = qr0 + 16 * 512;
      const float* wr  = attn_W + (size_t)(n0 + fr) * 1024 + kt + kof;
      float4 x0 = *(const float4*)qr0, x1 = *(const float4*)(qr0 + 4);
      float4 y0 = *(const float4*)qr1, y1 = *(const float4*)(qr1 + 4);
      float4 w0 = *(const float4*)wr,  w1 = *(const float4*)(wr + 4);
      bf16x8 A0 = pack_bf8(x0, x1), A1 = pack_bf8(y0, y1), Bb = pack_bf8(w0, w1);
      ac0 = __builtin_amdgcn_mfma_f32_16x16x32_bf16(A0, Bb, ac0, 0, 0, 0);
      ac1 = __builtin_amdgcn_mfma_f32_16x16x32_bf16(A1, Bb, ac1, 0, 0, 0);
    }
    float vb = attn_b[n0 + fr];
#pragma unroll
    for (int j = 0; j < 4; ++j) {
      qW[(size_t)(rb0 + g * 4 + j) * 512 + n0 + fr]      = ac0[j] + vb;
      qW[(size_t)(rb0 + 16 + g * 4 + j) * 512 + n0 + fr] = ac1[j] + vb;
    }
    return;
  }
  if (blk == 16) {                              // mask dtype detect
    __shared__ int sf;
    if (t == 0) sf = 0;
    __syncthreads();
    const uint32_t* m32 = (const uint32_t*)mask;
    int found = 0;
    for (int i = t; i < 16384; i += 512)
      if (m32[i] & 0xffffff00u) found = 1;      // nonzero byte at pos%4!=0 => byte mask
    if (found) sf = 1;
    __syncthreads();
    if (t == 0) *flag = sf;
    return;
  }
  // arena + biases + gather, one quad per thread
  const int ARENA_Q = 1507328;
  int i = (blk - 17) * 512 + t;
  if (i < ARENA_Q) {
    int e = i * 4;
    float4 v = {0.f, 0.f, 0.f, 0.f};
    if (e < 262144) {                           // Wenc = attn_W[:, 512:]
      int o = e >> 9, k = e & 511;
      v = *(const float4*)(attn_W + (size_t)o * 1024 + 512 + k);
    } else if (e < 786432) {                    // Wcat
      int e2 = e - 262144; int o = e2 >> 10, k = e2 & 1023;
      v = *(const float4*)(cat_W + (size_t)o * 1024 + k);
    } else if (e < 3932160) {                   // Wg0p [2048=4o+g][1536]
      int e2 = e - 786432; int row = e2 / 1536, k = e2 % 1536;
      int o = row >> 2, gt = row & 3;
      if (gt == 0)      v = (k < 1024) ? *(const float4*)(W_ih0 + (size_t)o * 1024 + k)
                                       : *(const float4*)(W_hh0 + (size_t)o * 512 + k - 1024);
      else if (gt == 1) v = (k < 1024) ? *(const float4*)(W_ih0 + (size_t)(512 + o) * 1024 + k)
                                       : *(const float4*)(W_hh0 + (size_t)(512 + o) * 512 + k - 1024);
      else if (gt == 2) { if (k < 1024)  v = *(const float4*)(W_ih0 + (size_t)(1024 + o) * 1024 + k); }
      else              { if (k >= 1024) v = *(const float4*)(W_hh0 + (size_t)(1024 + o) * 512 + k - 1024); }
    } else {                                    // Wg1p [2048=4o+g][1024]
      int e2 = e - 3932160; int row = e2 >> 10, k = e2 & 1023;
      int o = row >> 2, gt = row & 3;
      if (gt == 0)      v = (k < 512) ? *(const float4*)(W_ih1 + (size_t)o * 512 + k)
                                      : *(const float4*)(W_hh1 + (size_t)o * 512 + k - 512);
      else if (gt == 1) v = (k < 512) ? *(const float4*)(W_ih1 + (size_t)(512 + o) * 512 + k)
                                      : *(const float4*)(W_hh1 + (size_t)(512 + o) * 512 + k - 512);
      else if (gt == 2) { if (k < 512)  v = *(const float4*)(W_ih1 + (size_t)(1024 + o) * 512 + k); }
      else              { if (k >= 512) v = *(const float4*)(W_hh1 + (size_t)(1024 + o) * 512 + k - 512); }
    }
    ushort4 u;
    u.x = f2bf(v.x); u.y = f2bf(v.y); u.z = f2bf(v.z); u.w = f2bf(v.w);
    *(ushort4*)(arena + e) = u;
    return;
  }
  int i2 = i - ARENA_Q;
  if (i2 < 1024) {                              // biases, 4o+g quads
    int r4 = i2 * 4; int layer = r4 >> 11; int r = r4 & 2047; int o = r >> 2;
    const float* bi = layer ? b_ih1 : b_ih0;
    const float* bh = layer ? b_hh1 : b_hh0;
    float4 v;
    v.x = bi[o] + bh[o];
    v.y = bi[512 + o] + bh[512 + o];
    v.z = bi[1024 + o];
    v.w = bh[1024 + o];
    *(float4*)((layer ? biasg1 : biasg0) + r) = v;
  } else if (i2 < 1024 + 16384) {               // emb gather
    int j = (i2 - 1024) * 4; int b = j >> 9, i0 = j & 511;
    float4 v = *(const float4*)(wdv + (size_t)b * (Vdim * Hdim) + (size_t)ids[b] * 512 + i0);
    ushort4 u;
    u.x = f2bf(v.x); u.y = f2bf(v.y); u.z = f2bf(v.z); u.w = f2bf(v.w);
    *(ushort4*)(X0bf + b * 1536 + i0) = u;
  } else if (i2 < 1024 + 32768) {               // lh0 -> X0bf[:,1024:]
    int j = (i2 - 1024 - 16384) * 4; int b = j >> 9, i0 = j & 511;
    float4 v = *(const float4*)(lh + (size_t)b * 512 + i0);
    ushort4 u;
    u.x = f2bf(v.x); u.y = f2bf(v.y); u.z = f2bf(v.z); u.w = f2bf(v.w);
    *(ushort4*)(X0bf + b * 1536 + 1024 + i0) = u;
  } else if (i2 < 1024 + 49152) {               // q -> X1bf[:,512:]
    int j = (i2 - 1024 - 32768) * 4; int b = j >> 9, i0 = j & 511;
    float4 v = *(const float4*)(lh + 65536 + (size_t)b * 512 + i0);
    ushort4 u;
    u.x = f2bf(v.x); u.y = f2bf(v.y); u.z = f2bf(v.z); u.w = f2bf(v.w);
    *(ushort4*)(X1bf + b * 1024 + 512 + i0) = u;
  }
}

// =======================================================================
// attention energies. grid 1024: one (l, oh) 128x256 tile per block.
// l = (blk>>4)*8 + (blk&7); oh = (blk>>3)&1  -> both oh of an l on same XCD.
// A = enc f32 (reg-staged + cvt) -> LDS dbuf (shared by all 8 waves).
// B = Wenc bf16 DIRECT global->reg (no cross-wave sharing -> no LDS),
// prefetched one K-step ahead. LDS 24.5 KB. acc[8][2] = 64 VGPR.
// =======================================================================
__global__ __launch_bounds__(512)
void attn_kernel(const float* __restrict__ enc, const u16* __restrict__ Wenc,
                 const float* __restrict__ qW, const float* __restrict__ scW,
                 float* __restrict__ scores_p) {
  __shared__ __align__(16) u16 As[2][128 * 40];
  __shared__ float part[8 * 128];
  int blk = blockIdx.x, t = threadIdx.x;
  int lane = t & 63, wid = t >> 6;
  int fr = lane & 15, g = lane >> 4, kof = g * 8;
  int l  = (blk >> 4) * 8 + (blk & 7);
  int oh = (blk >> 3) & 1;
  int ob = oh * 256;
  const int arow = t >> 2;             // 0..127
  const int aks = (t & 3) * 8;

  f32x4 acc[8][2];
#pragma unroll
  for (int i = 0; i < 8; ++i) {
    acc[i][0] = (f32x4){0.f, 0.f, 0.f, 0.f};
    acc[i][1] = (f32x4){0.f, 0.f, 0.f, 0.f};
  }
  const float* abase = enc + ((size_t)l * 128 + arow) * 512 + aks;
  const u16* bptr0 = Wenc + (size_t)(ob + wid * 32 + fr) * 512 + kof;
  const u16* bptr1 = bptr0 + (size_t)16 * 512;

  float4 ra0 = *(const float4*)abase;
  float4 ra1 = *(const float4*)(abase + 4);
  bf16x8 cb0 = *(const bf16x8*)bptr0;
  bf16x8 cb1 = *(const bf16x8*)bptr1;

#pragma unroll 2
  for (int step = 0; step < 16; ++step) {
    int sel = step & 1;
    __syncthreads();
    uint4 ap;
    ap.x = pk2(ra0.x, ra0.y); ap.y = pk2(ra0.z, ra0.w);
    ap.z = pk2(ra1.x, ra1.y); ap.w = pk2(ra1.z, ra1.w);
    *(uint4*)(&As[sel][arow * 40 + aks]) = ap;
    bf16x8 nb0 = cb0, nb1 = cb1;
    if (step < 15) {
      int kt = (step + 1) * 32;
      ra0 = *(const float4*)(abase + kt);
      ra1 = *(const float4*)(abase + kt + 4);
      nb0 = *(const bf16x8*)(bptr0 + kt);
      nb1 = *(const bf16x8*)(bptr1 + kt);
    }
    __syncthreads();
#pragma unroll
    for (int mi = 0; mi < 8; ++mi) {
      bf16x8 av = *(const bf16x8*)(&As[sel][(mi * 16 + fr) * 40 + kof]);
      acc[mi][0] = __builtin_amdgcn_mfma_f32_16x16x32_bf16(av, cb0, acc[mi][0], 0, 0, 0);
      acc[mi][1] = __builtin_amdgcn_mfma_f32_16x16x32_bf16(av, cb1, acc[mi][1], 0, 0, 0);
    }
    cb0 = nb0; cb1 = nb1;
  }
  // epilogue: +qW, tanh, *scW, reduce over this block's 256 o's
#pragma unroll
  for (int mi = 0; mi < 8; ++mi) {
    float rs0 = 0.f, rs1 = 0.f, rs2 = 0.f, rs3 = 0.f;
#pragma unroll
    for (int ni = 0; ni < 2; ++ni) {
      int o = ob + wid * 32 + ni * 16 + fr;
      float sw = scW[o];
      int brow = mi * 16 + g * 4;
      rs0 += sw * fast_tanh(acc[mi][ni][0] + qW[(size_t)(brow + 0) * 512 + o]);
      rs1 += sw * fast_tanh(acc[mi][ni][1] + qW[(size_t)(brow + 1) * 512 + o]);
      rs2 += sw * fast_tanh(acc[mi][ni][2] + qW[(size_t)(brow + 2) * 512 + o]);
      rs3 += sw * fast_tanh(acc[mi][ni][3] + qW[(size_t)(brow + 3) * 512 + o]);
    }
#pragma unroll
    for (int d = 1; d < 16; d <<= 1) {
      rs0 += __shfl_xor(rs0, d);
      rs1 += __shfl_xor(rs1, d);
      rs2 += __shfl_xor(rs2, d);
      rs3 += __shfl_xor(rs3, d);
    }
    if (fr < 4) {
      float v = (fr == 0) ? rs0 : (fr == 1) ? rs1 : (fr == 2) ? rs2 : rs3;
      part[wid * 128 + mi * 16 + g * 4 + fr] = v;
    }
  }
  __syncthreads();
  if (t < 128) {
    float s = 0.f;
#pragma unroll
    for (int w2 = 0; w2 < 8; ++w2) s += part[w2 * 128 + t];
    scores_p[(size_t)(oh * 128 + t) * 512 + l] = s;
  }
}

// =======================================================================
// mask + softmax + context. grid 1024 = (b, 64-col chunk c).
// =======================================================================
__global__ __launch_bounds__(256)
void softctx_kernel(const float* __restrict__ sp, const void* __restrict__ maskp,
                    const int* __restrict__ flag, const float* __restrict__ enc,
                    u16* __restrict__ X0bf, u16* __restrict__ c1bf) {
  __shared__ float wgt[512];
  __shared__ float redm[4], reds[4];
  __shared__ float ps[256 * 2];
  int blk = blockIdx.x, t = threadIdx.x;
  int lane = t & 63, wid = t >> 6;
  int b = blk >> 3, c = blk & 7;
  int l0 = t, l1 = t + 256;
  float s0 = sp[(size_t)b * 512 + l0] + sp[(size_t)(128 + b) * 512 + l0];
  float s1 = sp[(size_t)b * 512 + l1] + sp[(size_t)(128 + b) * 512 + l1];
  bool isbyte = (*flag != 0);
  bool m0, m1;
  if (isbyte) {
    m0 = ((const uint8_t*)maskp)[b * 512 + l0] != 0;
    m1 = ((const uint8_t*)maskp)[b * 512 + l1] != 0;
  } else {
    m0 = ((const int*)maskp)[b * 512 + l0] != 0;
    m1 = ((const int*)maskp)[b * 512 + l1] != 0;
  }
  float v0 = m0 ? -1e12f : s0;
  float v1 = m1 ? -1e12f : s1;
  float mx = fmaxf(v0, v1);
#pragma unroll
  for (int d = 1; d < 64; d <<= 1) mx = fmaxf(mx, __shfl_xor(mx, d));
  if (lane == 0) redm[wid] = mx;
  __syncthreads();
  mx = fmaxf(fmaxf(redm[0], redm[1]), fmaxf(redm[2], redm[3]));
  float e0 = __expf(v0 - mx), e1 = __expf(v1 - mx);
  float sm = e0 + e1;
#pragma unroll
  for (int d = 1; d < 64; d <<= 1) sm += __shfl_xor(sm, d);
  if (lane == 0) reds[wid] = sm;
  __syncthreads();
  sm = reds[0] + reds[1] + reds[2] + reds[3];
  float inv = 1.0f / sm;
  wgt[l0] = e0 * inv;
  wgt[l1] = e1 * inv;
  __syncthreads();
  int cp = t & 31, lq = t >> 5;
  int col = c * 64 + cp * 2;
  float a0 = 0.f, a1 = 0.f;
  const float* ebase = enc + (size_t)b * 512 + col;
#pragma unroll 4
  for (int l2 = lq * 64; l2 < lq * 64 + 64; ++l2) {
    float wl = wgt[l2];
    float2 ev = *(const float2*)(ebase + (size_t)l2 * 65536);
    a0 += wl * ev.x;
    a1 += wl * ev.y;
  }
  ps[(lq * 32 + cp) * 2 + 0] = a0;
  ps[(lq * 32 + cp) * 2 + 1] = a1;
  __syncthreads();
  if (t < 32) {
    float r0 = 0.f, r1 = 0.f;
#pragma unroll
    for (int q2 = 0; q2 < 8; ++q2) {
      r0 += ps[(q2 * 32 + t) * 2 + 0];
      r1 += ps[(q2 * 32 + t) * 2 + 1];
    }
    int cc = c * 64 + t * 2;
    uint32_t packed = pk2(r0, r1);
    *(uint32_t*)(X0bf + b * 1536 + 512 + cc) = packed;
    *(uint32_t*)(c1bf + b * 1024 + 512 + cc) = packed;
  }
}

// =======================================================================
// GRU layer: GEMM (gate-interleaved W: row 4o+g) + fused combine epilogue.
// grid 64 blocks (8 outputs each), block 256 (4 waves x 32 rows).
// =======================================================================
__global__ __launch_bounds__(256)
void gru_gemm_kernel(const u16* __restrict__ X, int ldx, const u16* __restrict__ Wp,
                     const float* __restrict__ biasp, const float* __restrict__ hprev,
                     int K, float* __restrict__ hout, u16* __restrict__ xdst) {
  __shared__ float ct[128][36];
  int n0 = blockIdx.x * 32;
  int t = threadIdx.x, lane = t & 63, w = t >> 6;
  int fr = lane & 15, g = lane >> 4, kof = g * 8;
  f32x4 acc[2][2];
#pragma unroll
  for (int i = 0; i < 2; ++i)
#pragma unroll
    for (int j = 0; j < 2; ++j) acc[i][j] = (f32x4){0.f, 0.f, 0.f, 0.f};
  const u16* Xr0 = X + (size_t)(w * 32 + fr) * ldx;
  const u16* Xr1 = Xr0 + (size_t)16 * ldx;
  const u16* Wr0 = Wp + (size_t)(n0 + fr) * K;
  const u16* Wr1 = Wp + (size_t)(n0 + 16 + fr) * K;
#pragma unroll 4
  for (int kt = 0; kt < K; kt += 32) {
    bf16x8 a0 = *(const bf16x8*)(Xr0 + kt + kof);
    bf16x8 a1 = *(const bf16x8*)(Xr1 + kt + kof);
    bf16x8 b0 = *(const bf16x8*)(Wr0 + kt + kof);
    bf16x8 b1 = *(const bf16x8*)(Wr1 + kt + kof);
    acc[0][0] = __builtin_amdgcn_mfma_f32_16x16x32_bf16(a0, b0, acc[0][0], 0, 0, 0);
    acc[0][1] = __builtin_amdgcn_mfma_f32_16x16x32_bf16(a0, b1, acc[0][1], 0, 0, 0);
    acc[1][0] = __builtin_amdgcn_mfma_f32_16x16x32_bf16(a1, b0, acc[1][0], 0, 0, 0);
    acc[1][1] = __builtin_amdgcn_mfma_f32_16x16x32_bf16(a1, b1, acc[1][1], 0, 0, 0);
  }
#pragma unroll
  for (int mi = 0; mi < 2; ++mi)
#pragma unroll
    for (int ni = 0; ni < 2; ++ni) {
      int col = ni * 16 + fr;
      float vb = biasp[n0 + col];
#pragma unroll
      for (int j = 0; j < 4; ++j)
        ct[w * 32 + 16 * mi + g * 4 + j][col] = acc[mi][ni][j] + vb;
    }
  __syncthreads();
#pragma unroll
  for (int i = 0; i < 4; ++i) {
    int u = t + i * 256;
    int b = u >> 3, ol = u & 7;
    float cr  = ct[b][ol * 4 + 0];
    float cz  = ct[b][ol * 4 + 1];
    float ci  = ct[b][ol * 4 + 2];
    float chh = ct[b][ol * 4 + 3];
    int o = blockIdx.x * 8 + ol;
    float r = fast_sig(cr), z = fast_sig(cz);
    float n = tanhf(ci + r * chh);
    float h = (1.0f - z) * n + z * hprev[b * 512 + o];
    hout[b * 512 + o] = h;
    xdst[b * 1024 + o] = f2bf(h);
  }
}

// =======================================================================
// thin GEMM, N-tile 32: C = act(X @ W^T + bias). grid N/32, block 256.
// =======================================================================
__global__ __launch_bounds__(256)
void thin_gemm32(const u16* __restrict__ X, int ldx, const u16* __restrict__ W,
                 const float* __restrict__ bias, float* __restrict__ C, int ldc,
                 int K, int act) {
  int n0 = blockIdx.x * 32;
  int t = threadIdx.x, lane = t & 63, w = t >> 6;
  int fr = lane & 15, g = lane >> 4, kof = g * 8;
  f32x4 acc[2][2];
#pragma unroll
  for (int i = 0; i < 2; ++i)
#pragma unroll
    for (int j = 0; j < 2; ++j) acc[i][j] = (f32x4){0.f, 0.f, 0.f, 0.f};
  const u16* Xr0 = X + (size_t)(w * 32 + fr) * ldx;
  const u16* Xr1 = Xr0 + (size_t)16 * ldx;
  const u16* Wr0 = W + (size_t)(n0 + fr) * K;
  const u16* Wr1 = W + (size_t)(n0 + 16 + fr) * K;
#pragma unroll 4
  for (int kt = 0; kt < K; kt += 32) {
    bf16x8 a0 = *(const bf16x8*)(Xr0 + kt + kof);
    bf16x8 a1 = *(const bf16x8*)(Xr1 + kt + kof);
    bf16x8 b0 = *(const bf16x8*)(Wr0 + kt + kof);
    bf16x8 b1 = *(const bf16x8*)(Wr1 + kt + kof);
    acc[0][0] = __builtin_amdgcn_mfma_f32_16x16x32_bf16(a0, b0, acc[0][0], 0, 0, 0);
    acc[0][1] = __builtin_amdgcn_mfma_f32_16x16x32_bf16(a0, b1, acc[0][1], 0, 0, 0);
    acc[1][0] = __builtin_amdgcn_mfma_f32_16x16x32_bf16(a1, b0, acc[1][0], 0, 0, 0);
    acc[1][1] = __builtin_amdgcn_mfma_f32_16x16x32_bf16(a1, b1, acc[1][1], 0, 0, 0);
  }
#pragma unroll
  for (int mi = 0; mi < 2; ++mi)
#pragma unroll
    for (int ni = 0; ni < 2; ++ni) {
      int col = n0 + ni * 16 + fr;
      float vb = bias[col];
#pragma unroll
      for (int j = 0; j < 4; ++j) {
        int row = w * 32 + 16 * mi + g * 4 + j;
        float v = acc[mi][ni][j] + vb;
        if (act) v = tanhf(v);
        C[(size_t)row * ldc + col] = v;
      }
    }
}

extern "C" void kernel_launch(void* const* d_in, const int* in_sizes, int n_in,
                              void* d_out, int out_size, void* d_ws, size_t ws_size,
                              hipStream_t stream) {
  const int*   ids    = (const int*)  d_in[0];
  const float* lh     = (const float*)d_in[1];
  const float* wdv    = (const float*)d_in[2];
  const float* enc    = (const float*)d_in[3];
  const void*  mask   = d_in[4];
  const float* attn_W = (const float*)d_in[5];
  const float* attn_b = (const float*)d_in[6];
  const float* scW    = (const float*)d_in[7];
  const float* cat_W  = (const float*)d_in[8];
  const float* cat_b  = (const float*)d_in[9];
  const float* W_ih0  = (const float*)d_in[10];
  const float* W_hh0  = (const float*)d_in[11];
  const float* b_ih0  = (const float*)d_in[12];
  const float* b_hh0  = (const float*)d_in[13];
  const float* W_ih1  = (const float*)d_in[14];
  const float* W_hh1  = (const float*)d_in[15];
  const float* b_ih1  = (const float*)d_in[16];
  const float* b_hh1  = (const float*)d_in[17];

  float* out = (float*)d_out;
  float* h0  = out + 65536;
  float* h1  = out + 131072;

  float* ws       = (float*)d_ws;
  float* qW       = ws;                      // 65536
  float* scores_p = ws + 65536;              // 131072 [2][128][512]
  float* biasg0   = ws + 196608;             // 2048
  float* biasg1   = ws + 198656;             // 2048
  int*   flag     = (int*)(ws + 200704);     // 16
  u16*   arena    = (u16*)(ws + 200720);     // 6029312 u16
  u16*   X0bf     = (u16*)(ws + 3215376);    // 196608 u16
  u16*   X1bf     = (u16*)(ws + 3313680);    // 131072 u16
  u16*   c1bf     = (u16*)(ws + 3379216);    // 131072 u16

  const u16* Wenc = arena;
  const u16* Wcat = arena + 262144;
  const u16* Wg0p = arena + 786432;
  const u16* Wg1p = arena + 3932160;

  prep_kernel<<<3059, 512, 0, stream>>>(lh, attn_W, attn_b, cat_W,
                                        W_ih0, W_hh0, W_ih1, W_hh1,
                                        b_ih0, b_hh0, b_ih1, b_hh1,
                                        wdv, ids, mask,
                                        qW, arena, biasg0, biasg1, X0bf, X1bf, flag);
  attn_kernel<<<1024, 512, 0, stream>>>(enc, Wenc, qW, scW, scores_p);
  softctx_kernel<<<1024, 256, 0, stream>>>(scores_p, mask, flag, enc, X0bf, c1bf);
  gru_gemm_kernel<<<64, 256, 0, stream>>>(X0bf, 1536, Wg0p, biasg0, lh, 1536, h0, X1bf);
  gru_gemm_kernel<<<64, 256, 0, stream>>>(X1bf, 1024, Wg1p, biasg1, lh + 65536, 1024, h1, c1bf);
  thin_gemm32<<<16, 256, 0, stream>>>(c1bf, 1024, Wcat, cat_b, out, 512, 1024, 1);
}